// Round 6
// baseline (746.117 us; speedup 1.0000x reference)
//
#include <hip/hip_runtime.h>
#include <cstdint>
#include <cstddef>

#define DIM    128
#define HEADS  6
#define INNER  192
#define QKV3   576
#define FFI    341
#define FF2    682
#define GGP    352   // padded K for w2 (341 -> 352)
#define BATCH  2
#define T_IN   12800
#define N1     12992 // 32 * 406
#define N2     6496  // 32 * 203
#define ROWS1  (BATCH * N1)  // 25984 = 64*406
#define ROWS2  (BATCH * N2)  // 12992 = 64*203
#define W_DT   406
#define W_LT   203

typedef unsigned short ushortT;
typedef unsigned int u32;
typedef __bf16 bf16x8 __attribute__((ext_vector_type(8)));
typedef float f32x4 __attribute__((ext_vector_type(4)));

__device__ __forceinline__ f32x4 mfma16(bf16x8 a, bf16x8 b, f32x4 c) {
  return __builtin_amdgcn_mfma_f32_16x16x32_bf16(a, b, c, 0, 0, 0);
}
__device__ __forceinline__ ushortT f2bf(float x) {
  union { __bf16 b; ushortT u; } c; c.b = (__bf16)x; return c.u;
}
__device__ __forceinline__ void async_copy16(const ushortT* g, ushortT* l) {
  __builtin_amdgcn_global_load_lds(
      (const __attribute__((address_space(1))) unsigned int*)g,
      (__attribute__((address_space(3))) unsigned int*)l, 16, 0, 0);
}

// ---------------- workspace layout (float units) ----------------
static constexpr size_t OF_FEAT = 0;                                    // f32 ROWS1*128
static constexpr size_t OF_H    = OF_FEAT + (size_t)ROWS1 * DIM;        // bf16 ROWS1*128
static constexpr size_t OF_QKH  = OF_H + (size_t)ROWS1 * DIM / 2;       // bf16 (ROWS1+128)*384
static constexpr size_t SZ_QKH  = ((size_t)(ROWS1 + 128) * 384) / 2;
static constexpr size_t OF_AO   = OF_QKH + SZ_QKH;                      // bf16 ROWS1*192
static constexpr size_t OF_VT   = OF_AO + (size_t)ROWS1 * INNER / 2;    // bf16 384*(N1+128)
static constexpr size_t SZ_VT   = ((size_t)384 * (N1 + 128)) / 2;
static constexpr size_t OF_GG   = OF_VT + SZ_VT;                        // bf16 ROWS1*352
static constexpr size_t OF_F2   = OF_GG + (size_t)ROWS1 * GGP / 2;      // f32 ROWS2*128
static constexpr size_t OF_WT   = OF_F2 + (size_t)ROWS2 * DIM;          // bf16 weights
static constexpr size_t WT_QKV = 0;        // 640*128
static constexpr size_t WT_WO  = 81920;    // 128*192
static constexpr size_t WT_W1  = 106496;   // 768*128 (interleaved a/gate)
static constexpr size_t WT_W2  = 204800;   // 128*352
static constexpr size_t WT_SET = 249856;   // ushorts per layer-set
static constexpr size_t OF_CW  = OF_WT + (4 * WT_SET) / 2 + 64;         // bf16 conv 128*256
static constexpr size_t OF_ROPE = OF_CW + (128 * 256) / 2 + 64;         // f32 N1*16 float2
static constexpr size_t OF_H2  = OF_ROPE + (size_t)N1 * 32;             // bf16 ROWS2*128

// ---------------- build feat ----------------
__global__ void build_feat_kernel(const float* __restrict__ x,
                                  const float* __restrict__ cache,
                                  float* __restrict__ feat) {
  int idx = blockIdx.x * 256 + threadIdx.x;
  if (idx >= ROWS1 * DIM) return;
  int d = idx & 127;
  int row = idx >> 7;
  int b = row / N1;
  int i = row - b * N1;
  int c = i / 406;
  int j = i - c * 406;
  float v;
  if (j < 6) v = cache[j * DIM + d];
  else       v = x[((size_t)b * DIM + d) * T_IN + (c * 400 + j - 6)];
  feat[idx] = v;
}

// ---------------- layernorm -> bf16 (standalone; 1 use remains) ----------------
__global__ __launch_bounds__(256) void ln_kernel(const float* __restrict__ x,
                                                 ushortT* __restrict__ y,
                                                 const float* __restrict__ w,
                                                 const float* __restrict__ bb,
                                                 int rows) {
  int row = blockIdx.x * 4 + (threadIdx.x >> 6);
  if (row >= rows) return;
  int lane = threadIdx.x & 63;
  const float* xr = x + (size_t)row * DIM;
  float2 v = *(const float2*)(xr + lane * 2);
  float s = v.x + v.y;
#pragma unroll
  for (int off = 32; off; off >>= 1) s += __shfl_xor(s, off);
  float mean = s * (1.0f / 128.0f);
  float dx = v.x - mean, dy = v.y - mean;
  float q = dx * dx + dy * dy;
#pragma unroll
  for (int off = 32; off; off >>= 1) q += __shfl_xor(q, off);
  float rstd = rsqrtf(q * (1.0f / 128.0f) + 1e-5f);
  float2 wv = *(const float2*)(w + lane * 2);
  float2 bv = *(const float2*)(bb + lane * 2);
  u32 packed = (u32)f2bf(dx * rstd * wv.x + bv.x) |
               ((u32)f2bf(dy * rstd * wv.y + bv.y) << 16);
  *(u32*)(y + (size_t)row * DIM + lane * 2) = packed;
}

// ---------------- bf16 GEMM 64xN128: residual + bias + fused LN + bf16 mirror ----------------
// Co (nullable) [M,128] = A @ Wt^T (+C, +bias). hout (nullable): LN of result.
// bfout (nullable): bf16 copy of result (pre-LN).
__global__ __launch_bounds__(256) void gemm_nln(
    const ushortT* __restrict__ A, int lda,
    const ushortT* __restrict__ Wt, int ldw,
    const float* __restrict__ C, float* __restrict__ Co,
    const float* __restrict__ bias,
    int M, int Kpad, int addC,
    const float* __restrict__ lnw, const float* __restrict__ lnb,
    ushortT* __restrict__ hout, ushortT* __restrict__ bfout) {
  __shared__ ushortT As[64 * 32];
  __shared__ ushortT Bs[128 * 32];
  __shared__ float lnS[64][4];           // [rowInBlock][half*2 + stat]
  const int tid = threadIdx.x;
  const int wid = tid >> 6, lane = tid & 63;
  const int ck = lane & 15, quad = lane >> 4;
  const int bm = blockIdx.y * 64;
  const int wr = (wid >> 1) * 32, wc = (wid & 1) * 64;
  const int half = wid & 1;
  f32x4 acc[2][4];
#pragma unroll
  for (int t = 0; t < 2; t++)
#pragma unroll
    for (int u = 0; u < 4; u++) acc[t][u] = (f32x4){0.f, 0.f, 0.f, 0.f};

  for (int k0 = 0; k0 < Kpad; k0 += 32) {
    __syncthreads();
    {
      int idx = wid * 64 + lane;
      int row = idx >> 2, seg = (idx & 3) << 3;
      async_copy16(A + (size_t)(bm + row) * lda + k0 + seg, As + (size_t)(wid * 64) * 8);
    }
#pragma unroll
    for (int c2 = 0; c2 < 2; c2++) {
      int idx = c2 * 256 + wid * 64 + lane;
      int row = idx >> 2, seg = (idx & 3) << 3;
      async_copy16(Wt + (size_t)row * ldw + k0 + seg, Bs + (size_t)(c2 * 256 + wid * 64) * 8);
    }
    __syncthreads();
    bf16x8 af[2], bfr[4];
#pragma unroll
    for (int t = 0; t < 2; t++)
      af[t] = *(const bf16x8*)&As[(wr + t * 16 + ck) * 32 + quad * 8];
#pragma unroll
    for (int u = 0; u < 4; u++)
      bfr[u] = *(const bf16x8*)&Bs[(wc + u * 16 + ck) * 32 + quad * 8];
#pragma unroll
    for (int t = 0; t < 2; t++)
#pragma unroll
      for (int u = 0; u < 4; u++)
        acc[t][u] = mfma16(af[t], bfr[u], acc[t][u]);
  }

  float bv4[4] = {0.f, 0.f, 0.f, 0.f};
  if (bias) {
#pragma unroll
    for (int u = 0; u < 4; u++) bv4[u] = bias[wc + u * 16 + ck];
  }
  float res[2][4][4];
#pragma unroll
  for (int t = 0; t < 2; t++) {
#pragma unroll
    for (int r = 0; r < 4; r++) {
      int row = bm + wr + t * 16 + quad * 4 + r;     // M % 64 == 0: always valid
      const float* crow = C + (size_t)row * DIM;
#pragma unroll
      for (int u = 0; u < 4; u++) {
        int col = wc + u * 16 + ck;
        float v = acc[t][u][r] + bv4[u];
        if (addC) v += crow[col];
        res[t][r][u] = v;
      }
      if (Co) {
        float* orow = Co + (size_t)row * DIM;
#pragma unroll
        for (int u = 0; u < 4; u++) orow[wc + u * 16 + ck] = res[t][r][u];
      }
      if (bfout) {
        ushortT* brow = bfout + (size_t)row * DIM;
#pragma unroll
        for (int u = 0; u < 4; u++) brow[wc + u * 16 + ck] = f2bf(res[t][r][u]);
      }
    }
  }

  if (hout) {
#pragma unroll
    for (int t = 0; t < 2; t++) {
#pragma unroll
      for (int r = 0; r < 4; r++) {
        float s1 = ((res[t][r][0] + res[t][r][1]) + (res[t][r][2] + res[t][r][3]));
        float s2 = ((res[t][r][0] * res[t][r][0] + res[t][r][1] * res[t][r][1]) +
                    (res[t][r][2] * res[t][r][2] + res[t][r][3] * res[t][r][3]));
        s1 += __shfl_xor(s1, 1); s2 += __shfl_xor(s2, 1);
        s1 += __shfl_xor(s1, 2); s2 += __shfl_xor(s2, 2);
        s1 += __shfl_xor(s1, 4); s2 += __shfl_xor(s2, 4);
        s1 += __shfl_xor(s1, 8); s2 += __shfl_xor(s2, 8);
        if (ck == 0) {
          int rowIn = wr + t * 16 + quad * 4 + r;
          lnS[rowIn][half * 2]     = s1;
          lnS[rowIn][half * 2 + 1] = s2;
        }
      }
    }
    __syncthreads();
    float lw[4], lb[4];
#pragma unroll
    for (int u = 0; u < 4; u++) {
      lw[u] = lnw[wc + u * 16 + ck];
      lb[u] = lnb[wc + u * 16 + ck];
    }
#pragma unroll
    for (int t = 0; t < 2; t++) {
#pragma unroll
      for (int r = 0; r < 4; r++) {
        int rowIn = wr + t * 16 + quad * 4 + r;
        float S1 = lnS[rowIn][0] + lnS[rowIn][2];
        float S2 = lnS[rowIn][1] + lnS[rowIn][3];
        float mean = S1 * (1.0f / 128.0f);
        float var = S2 * (1.0f / 128.0f) - mean * mean;
        float rstd = rsqrtf(var + 1e-5f);
        ushortT* hrow = hout + (size_t)(bm + rowIn) * DIM;
#pragma unroll
        for (int u = 0; u < 4; u++) {
          int col = wc + u * 16 + ck;
          hrow[col] = f2bf((res[t][r][u] - mean) * rstd * lw[u] + lb[u]);
        }
      }
    }
  }
}

// ---------------- fused qkv GEMM: rope(table) + bf16 + V-transpose epilogue ----------------
__global__ __launch_bounds__(256) void gemm_qkv(
    const ushortT* __restrict__ A,        // [M][128] bf16
    const ushortT* __restrict__ Wt,       // [640][128] bf16
    const float2* __restrict__ rope,      // [N1][16] (cos,sin)
    ushortT* __restrict__ qkh,            // [(M+128)][384]
    ushortT* __restrict__ vt,             // [384][nseqP]
    int M, int nseq, int nseqP) {
  __shared__ ushortT As[128 * 32];
  __shared__ ushortT Bs[128 * 32];
  const int tid = threadIdx.x;
  const int wid = tid >> 6, lane = tid & 63;
  const int ck = lane & 15, quad = lane >> 4;
  const int bm = blockIdx.y * 128, bn = blockIdx.x * 128;
  const int wr = (wid >> 1) * 64, wc = (wid & 1) * 64;
  f32x4 acc[4][4];
#pragma unroll
  for (int t = 0; t < 4; t++)
#pragma unroll
    for (int u = 0; u < 4; u++) acc[t][u] = (f32x4){0.f, 0.f, 0.f, 0.f};

  for (int k0 = 0; k0 < 128; k0 += 32) {
    __syncthreads();
#pragma unroll
    for (int c2 = 0; c2 < 2; c2++) {
      int idx = c2 * 256 + wid * 64 + lane;
      int row = idx >> 2, seg = (idx & 3) << 3;
      int ar = bm + row; if (ar > M - 1) ar = M - 1;
      async_copy16(A + (size_t)ar * 128 + k0 + seg, As + (size_t)(c2 * 256 + wid * 64) * 8);
      async_copy16(Wt + (size_t)(bn + row) * 128 + k0 + seg, Bs + (size_t)(c2 * 256 + wid * 64) * 8);
    }
    __syncthreads();
    bf16x8 af[4], bfr[4];
#pragma unroll
    for (int t = 0; t < 4; t++)
      af[t] = *(const bf16x8*)&As[(wr + t * 16 + ck) * 32 + quad * 8];
#pragma unroll
    for (int u = 0; u < 4; u++)
      bfr[u] = *(const bf16x8*)&Bs[(wc + u * 16 + ck) * 32 + quad * 8];
#pragma unroll
    for (int t = 0; t < 4; t++)
#pragma unroll
      for (int u = 0; u < 4; u++)
        acc[t][u] = mfma16(af[t], bfr[u], acc[t][u]);
  }

  const int s = bn + wc;
  if (s >= QKV3) return;

  if (s < 384) {
    const bool isQ = s < 192;
    const float SCq = 0.17677669529663687f * 1.4426950408889634f; // 32^-0.5 * log2e
#pragma unroll
    for (int t = 0; t < 4; t++) {
#pragma unroll
      for (int r = 0; r < 4; r++) {
        int row = bm + wr + t * 16 + quad * 4 + r;
        if (row >= M) continue;
        int pos = (row >= nseq) ? row - nseq : row;
        float2 cssn = rope[pos * 16 + ck];
        float cs = cssn.x, sn = cssn.y;
        ushortT* orow = qkh + (size_t)row * 384;
#pragma unroll
        for (int u = 0; u < 4; u += 2) {
          float a0 = acc[t][u][r], a1 = acc[t][u + 1][r];
          float o0 = a0 * cs - a1 * sn;
          float o1 = a1 * cs + a0 * sn;
          if (isQ) { o0 *= SCq; o1 *= SCq; }
          int c0 = s + u * 16 + ck;
          orow[c0]      = f2bf(o0);
          orow[c0 + 16] = f2bf(o1);
        }
      }
    }
  } else {
#pragma unroll
    for (int t = 0; t < 4; t++) {
      int rowb = bm + wr + t * 16 + quad * 4;
      if (rowb >= M) continue;
      int bb = (rowb >= nseq) ? 1 : 0;
      int posb = rowb - bb * nseq;
#pragma unroll
      for (int u = 0; u < 4; u++) {
        int cv = s - 384 + u * 16 + ck;
        int hh = cv >> 5, d = cv & 31;
        ushort4 o;
        o.x = f2bf(acc[t][u][0]);
        o.y = f2bf(acc[t][u][1]);
        o.z = f2bf(acc[t][u][2]);
        o.w = f2bf(acc[t][u][3]);
        *(ushort4*)(vt + ((size_t)((bb * 6 + hh) * 32 + d)) * nseqP + posb) = o;
      }
    }
  }
}

// ---------------- fused w1 GEMM + exact-GEGLU epilogue ----------------
__global__ __launch_bounds__(256) void gemm_w1g(
    const ushortT* __restrict__ A,
    const ushortT* __restrict__ Wt,       // [768][128] interleaved a/gate
    ushortT* __restrict__ gg,             // [M][GGP]
    int M) {
  __shared__ ushortT As[128 * 32];
  __shared__ ushortT Bs[128 * 32];
  const int tid = threadIdx.x;
  const int wid = tid >> 6, lane = tid & 63;
  const int ck = lane & 15, quad = lane >> 4;
  const int bm = blockIdx.y * 128, bn = blockIdx.x * 128;
  const int wr = (wid >> 1) * 64, wc = (wid & 1) * 64;
  f32x4 acc[4][4];
#pragma unroll
  for (int t = 0; t < 4; t++)
#pragma unroll
    for (int u = 0; u < 4; u++) acc[t][u] = (f32x4){0.f, 0.f, 0.f, 0.f};

  for (int k0 = 0; k0 < 128; k0 += 32) {
    __syncthreads();
#pragma unroll
    for (int c2 = 0; c2 < 2; c2++) {
      int idx = c2 * 256 + wid * 64 + lane;
      int row = idx >> 2, seg = (idx & 3) << 3;
      int ar = bm + row; if (ar > M - 1) ar = M - 1;
      async_copy16(A + (size_t)ar * 128 + k0 + seg, As + (size_t)(c2 * 256 + wid * 64) * 8);
      async_copy16(Wt + (size_t)(bn + row) * 128 + k0 + seg, Bs + (size_t)(c2 * 256 + wid * 64) * 8);
    }
    __syncthreads();
    bf16x8 af[4], bfr[4];
#pragma unroll
    for (int t = 0; t < 4; t++)
      af[t] = *(const bf16x8*)&As[(wr + t * 16 + ck) * 32 + quad * 8];
#pragma unroll
    for (int u = 0; u < 4; u++)
      bfr[u] = *(const bf16x8*)&Bs[(wc + u * 16 + ck) * 32 + quad * 8];
#pragma unroll
    for (int t = 0; t < 4; t++)
#pragma unroll
      for (int u = 0; u < 4; u++)
        acc[t][u] = mfma16(af[t], bfr[u], acc[t][u]);
  }

  const int s = bn + wc;
  if (s >= 704) return;
#pragma unroll
  for (int t = 0; t < 4; t++) {
#pragma unroll
    for (int r = 0; r < 4; r++) {
      int row = bm + wr + t * 16 + quad * 4 + r;
      if (row >= M) continue;
      ushortT* orow = gg + (size_t)row * GGP;
#pragma unroll
      for (int u = 0; u < 4; u += 2) {
        float a  = acc[t][u][r];
        float gt = acc[t][u + 1][r];
        float ge = 0.5f * gt * (1.0f + erff(gt * 0.70710678118654752f));
        int p = ((s + u * 16) >> 5) * 16 + ck;
        orow[p] = f2bf(a * ge);
      }
    }
  }
}

// ---------------- MFMA flash attention (R16: LDS-free, barrier-free —
//                  per-wave direct global->register K/V fragments, ping-pong
//                  1-tile prefetch; in-register softmax + ones-MFMA l-sum) ----------------
// K fragment addressing: lane(ck,quad), frag t reads logical key
//   lam = 32*(t>>1) + 8*(ck>>2) + 4*(t&1) + (ck&3)   (same permutation as R13/R14,
// applied at the global address). Mask key for D reg (t,quad,r):
//   key = tb + 32*(t>>1) + 4*(t&1) + 8*quad + r      (verified R13/R14).
__global__ __launch_bounds__(256) void attn_kernel(
    const ushortT* __restrict__ qkh, const ushortT* __restrict__ vt,
    ushortT* __restrict__ out, int nseq, int nseqP, int w, int nw, int qgroups) {
  const int bx = blockIdx.x;
  const int c = bx % nw;                    // chunk -> XCD affinity
  const int g = (qgroups - 1) - bx / nw;    // heaviest q-groups launch first
  const int h = blockIdx.y;
  const int b = blockIdx.z;
  const int tid = threadIdx.x;
  const int wv = tid >> 6;
  const int lane = tid & 63;
  const int ck = lane & 15;
  const int quad = lane >> 4;

  const int cw = c * w;
  const int q0 = g * 64;
  const int qt = q0 + wv * 16;
  if (qt >= w) return;                      // no barriers: free to exit

  const ushortT* gq = qkh + (size_t)b * nseq * 384;
  const ushortT* gv = vt + ((size_t)(b * 6 + h) * 32) * nseqP;
  const int j0 = (c > 0) ? (c - 1) * w : 0;
  const int jend = cw + min(qt + 15, w - 1) + 1;
  const int ntiles = (jend - j0 + 63) >> 6;

  bf16x8 qf;   // Q[qt+ck][d = quad*8..+7] as MFMA B operand (col = q)
  {
    int qrow = cw + min(qt + ck, w - 1);
    qf = *(const bf16x8*)(gq + (size_t)qrow * 384 + h * 32 + quad * 8);
  }

  // per-lane fragment bases
  const ushortT* kb_ = gq + (size_t)(8 * (ck >> 2) + (ck & 3)) * 384 + 192 + h * 32 + quad * 8;
  const ushortT* vb_ = gv + (size_t)ck * nseqP + quad * 8;
  const size_t VH = (size_t)16 * nseqP;     // +16 d-rows for the hi half

  f32x4 olo = {0.f, 0.f, 0.f, 0.f};
  f32x4 ohi = {0.f, 0.f, 0.f, 0.f};
  f32x4 accl = {0.f, 0.f, 0.f, 0.f};
  bf16x8 onesf;
  {
    union { u32 u[4]; bf16x8 v; } o_;
    o_.u[0] = o_.u[1] = o_.u[2] = o_.u[3] = 0x3F803F80u;  // bf16(1.0) x2
    onesf = o_.v;
  }

#define LOADK(tb, kf)                                                      \
  {                                                                        \
    const ushortT* p_ = kb_ + (size_t)(tb) * 384;                          \
    kf[0] = *(const bf16x8*)(p_);                                          \
    kf[1] = *(const bf16x8*)(p_ + (size_t)4 * 384);                        \
    kf[2] = *(const bf16x8*)(p_ + (size_t)32 * 384);                       \
    kf[3] = *(const bf16x8*)(p_ + (size_t)36 * 384);                       \
  }
#define LOADV(tb, vf)                                                      \
  {                                                                        \
    const ushortT* p_ = vb_ + (tb);                                        \
    vf[0] = *(const bf16x8*)(p_);                                          \
    vf[1] = *(const bf16x8*)(p_ + 32);                                     \
    vf[2] = *(const bf16x8*)(p_ + VH);                                     \
    vf[3] = *(const bf16x8*)(p_ + VH + 32);                                \
  }

  auto compute = [&](int tb, const bf16x8* kf, const bf16x8* vf) {
    f32x4 z = {0.f, 0.f, 0.f, 0.f};
    f32x4 s0 = mfma16(kf[0], qf, z);   // D[perm-key][q]: lane holds q=qt+ck
    f32x4 s1 = mfma16(kf[1], qf, z);
    f32x4 s2 = mfma16(kf[2], qf, z);
    f32x4 s3 = mfma16(kf[3], qf, z);
    if (tb + 63 > cw + qt) {
      int q = cw + qt + ck;
      int kb = tb + 8 * quad;
#pragma unroll
      for (int r = 0; r < 4; r++) {
        if (kb + r > q)      s0[r] = -__builtin_inff();
        if (kb + 4 + r > q)  s1[r] = -__builtin_inff();
        if (kb + 32 + r > q) s2[r] = -__builtin_inff();
        if (kb + 36 + r > q) s3[r] = -__builtin_inff();
      }
    }
    float e00 = exp2f(s0[0]), e01 = exp2f(s0[1]), e02 = exp2f(s0[2]), e03 = exp2f(s0[3]);
    float e10 = exp2f(s1[0]), e11 = exp2f(s1[1]), e12 = exp2f(s1[2]), e13 = exp2f(s1[3]);
    float e20 = exp2f(s2[0]), e21 = exp2f(s2[1]), e22 = exp2f(s2[2]), e23 = exp2f(s2[3]);
    float e30 = exp2f(s3[0]), e31 = exp2f(s3[1]), e32 = exp2f(s3[2]), e33 = exp2f(s3[3]);
    union { bf16x8 v; u32 u[4]; } pa0, pa1;
    pa0.u[0] = (u32)f2bf(e00) | ((u32)f2bf(e01) << 16);
    pa0.u[1] = (u32)f2bf(e02) | ((u32)f2bf(e03) << 16);
    pa0.u[2] = (u32)f2bf(e10) | ((u32)f2bf(e11) << 16);
    pa0.u[3] = (u32)f2bf(e12) | ((u32)f2bf(e13) << 16);
    pa1.u[0] = (u32)f2bf(e20) | ((u32)f2bf(e21) << 16);
    pa1.u[1] = (u32)f2bf(e22) | ((u32)f2bf(e23) << 16);
    pa1.u[2] = (u32)f2bf(e30) | ((u32)f2bf(e31) << 16);
    pa1.u[3] = (u32)f2bf(e32) | ((u32)f2bf(e33) << 16);
    olo  = mfma16(pa0.v, vf[0], olo);
    olo  = mfma16(pa1.v, vf[1], olo);
    ohi  = mfma16(pa0.v, vf[2], ohi);
    ohi  = mfma16(pa1.v, vf[3], ohi);
    accl = mfma16(pa0.v, onesf, accl);   // row-sum on the MFMA pipe
    accl = mfma16(pa1.v, onesf, accl);
  };

  // ping-pong pipeline: loads for tile i+1 issued before compute of tile i
  bf16x8 kA[4], vA[4], kB[4], vB[4];
  LOADK(j0, kA); LOADV(j0, vA);
  for (int i = 0; i < ntiles; i += 2) {
    {
      int tn = j0 + 64 * min(i + 1, ntiles - 1);
      LOADK(tn, kB); LOADV(tn, vB);
    }
    compute(j0 + i * 64, kA, vA);
    {
      int tn = j0 + 64 * min(i + 2, ntiles - 1);
      LOADK(tn, kA); LOADV(tn, vA);
    }
    if (i + 1 < ntiles) compute(j0 + (i + 1) * 64, kB, vB);
  }
#undef LOADK
#undef LOADV

  // epilogue: accl[r] is l for q = qt+quad*4+r (same layout as olo/ohi)
#pragma unroll
  for (int r = 0; r < 4; r++) {
    int qi = qt + quad * 4 + r;
    if (qi < w) {
      float invr = 1.0f / accl[r];
      ushortT* orow = out + ((size_t)b * nseq + cw + qi) * INNER + h * 32;
      orow[ck]      = f2bf(olo[r] * invr);
      orow[ck + 16] = f2bf(ohi[r] * invr);
    }
  }
}

// ---------------- merged setup: weights + conv bf16 + rope table ----------------
__global__ void wconvert_all_kernel(
    const float* __restrict__ dq, const float* __restrict__ dwo,
    const float* __restrict__ dw1, const float* __restrict__ dw2,
    const float* __restrict__ lq, const float* __restrict__ lwo,
    const float* __restrict__ lw1, const float* __restrict__ lw2,
    const float* __restrict__ convw,
    ushortT* __restrict__ wt, ushortT* __restrict__ cwt,
    float2* __restrict__ rope) {
  int idx = blockIdx.x * 256 + threadIdx.x;
  const int TOTW = 4 * (int)WT_SET;
  const int CWN = 128 * 256;
  if (idx < TOTW) {
    int s = idx / (int)WT_SET;
    int rem = idx - s * (int)WT_SET;
    int lyr = s & 1;
    const float* Wq = ((s < 2) ? dq : lq) + (size_t)lyr * DIM * QKV3;
    const float* Wo = ((s < 2) ? dwo : lwo) + (size_t)lyr * INNER * DIM;
    const float* W1 = ((s < 2) ? dw1 : lw1) + (size_t)lyr * DIM * FF2;
    const float* W2 = ((s < 2) ? dw2 : lw2) + (size_t)lyr * FFI * DIM;
    float v = 0.f;
    if (rem < (int)WT_WO) {                 // qkv: [640][128]
      int n = rem >> 7, k = rem & 127;
      if (n < QKV3) v = Wq[(size_t)k * QKV3 + n];
    } else if (rem < (int)WT_W1) {          // wo: [128][192]
      int r = rem - (int)WT_WO;
      int n = r / INNER, k = r - n * INNER;
      v = Wo[(size_t)k * DIM + n];
    } else if (rem < (int)WT_W2) {          // w1 interleaved: [768][128]
      int r = rem - (int)WT_W1;
      int n = r >> 7, k = r & 127;
      if (n < 704) {
        int blk = n >> 5, wi = n & 31;
        int p = blk * 16 + (wi & 15);
        if (p < FFI) {
          int src = (wi < 16) ? p : FFI + p;
          v = W1[(size_t)k * FF2 + src];
        }
      }
    } else {                                // w2: [128][352]
      int r = rem - (int)WT_W2;
      int n = r / GGP, k = r - n * GGP;
      if (k < FFI) v = W2[(size_t)k * DIM + n];
    }
    wt[idx] = f2bf(v);
  } else if (idx < TOTW + CWN) {
    // conv weights -> bf16 transposed: cwt[o][kk*128+i] = convw[(o*128+i)*2+kk]
    int r = idx - TOTW;
    int o = r >> 8, k = r & 255;
    int kk = k >> 7, i = k & 127;
    cwt[r] = f2bf(convw[((size_t)o * DIM + i) * 2 + kk]);
  } else {
    int r = idx - TOTW - CWN;
    if (r < N1 * 16) {
      int pos = r >> 4, k = r & 15;
      float invf = 1.0f / powf(10000.0f, (float)k * (1.0f / 16.0f));
      float sn, cs;
      sincosf((float)pos * invf, &sn, &cs);
      rope[r] = make_float2(cs, sn);
    }
  }
}

// ---------------- host-side layer driver ----------------
// hbuf = this layer's LN1 input activations (bf16). wo fuses ln2 -> hbuf;
// w2 fuses next-layer ln1 -> hbuf (if nlnw) and/or writes bf16 mirror (w2bf).
static void run_layer(float* F, float* Fout, ushortT* hbuf, ushortT* qkh, ushortT* vtb,
                      ushortT* attnb, ushortT* ggb, const ushortT* wt,
                      const float2* rope,
                      int M, int nseq, int w,
                      const float* ln2w, const float* ln2b,
                      const float* nlnw, const float* nlnb,
                      ushortT* w2bf, hipStream_t stream) {
  int nseqP = nseq + 128;
  int gy = (M + 127) / 128;
  int gy64 = M / 64;
  gemm_qkv<<<dim3(5, gy), 256, 0, stream>>>(hbuf, wt + WT_QKV, rope, qkh, vtb, M, nseq, nseqP);
  int nw = nseq / w;
  int qgroups = (w + 63) / 64;
  attn_kernel<<<dim3(nw * qgroups, HEADS, BATCH), 256, 0, stream>>>(qkh, vtb, attnb,
                                                                    nseq, nseqP, w, nw, qgroups);
  gemm_nln<<<dim3(1, gy64), 256, 0, stream>>>(attnb, INNER, wt + WT_WO, INNER, F, F,
                                              nullptr, M, INNER, 1, ln2w, ln2b,
                                              hbuf, nullptr);
  gemm_w1g<<<dim3(6, gy), 256, 0, stream>>>(hbuf, wt + WT_W1, ggb, M);
  gemm_nln<<<dim3(1, gy64), 256, 0, stream>>>(ggb, GGP, wt + WT_W2, GGP, F, Fout,
                                              nullptr, M, GGP, 1, nlnw, nlnb,
                                              nlnw ? hbuf : (ushortT*)nullptr, w2bf);
}

extern "C" void kernel_launch(void* const* d_in, const int* in_sizes, int n_in,
                              void* d_out, int out_size, void* d_ws, size_t ws_size,
                              hipStream_t stream) {
  const float* x        = (const float*)d_in[0];
  const float* cache    = (const float*)d_in[1];
  const float* dt_ln1_w = (const float*)d_in[2];
  const float* dt_ln1_b = (const float*)d_in[3];
  const float* dt_wqkv  = (const float*)d_in[4];
  const float* dt_wo    = (const float*)d_in[5];
  const float* dt_ln2_w = (const float*)d_in[6];
  const float* dt_ln2_b = (const float*)d_in[7];
  const float* dt_w1    = (const float*)d_in[8];
  const float* dt_w2    = (const float*)d_in[9];
  const float* lt_ln1_w = (const float*)d_in[10];
  const float* lt_ln1_b = (const float*)d_in[11];
  const float* lt_wqkv  = (const float*)d_in[12];
  const float* lt_wo    = (const float*)d_in[13];
  const float* lt_ln2_w = (const float*)d_in[14];
  const float* lt_ln2_b = (const float*)d_in[15];
  const float* lt_w1    = (const float*)d_in[16];
  const float* lt_w2    = (const float*)d_in[17];
  const float* conv_w   = (const float*)d_in[18];
  const float* conv_b   = (const float*)d_in[19];

  float* ws     = (float*)d_ws;
  float* feat   = ws + OF_FEAT;
  ushortT* h    = (ushortT*)(ws + OF_H);
  ushortT* qkh  = (ushortT*)(ws + OF_QKH);
  ushortT* attnb= (ushortT*)(ws + OF_AO);
  ushortT* vtb  = (ushortT*)(ws + OF_VT);
  ushortT* ggb  = (ushortT*)(ws + OF_GG);
  float* feat2  = ws + OF_F2;
  ushortT* wt   = (ushortT*)(ws + OF_WT);
  ushortT* cwt  = (ushortT*)(ws + OF_CW);
  float2* rope  = (float2*)(ws + OF_ROPE);
  ushortT* h2   = (ushortT*)(ws + OF_H2);
  float* outf   = (float*)d_out;

  {
    int total = 4 * (int)WT_SET + 128 * 256 + N1 * 16;
    wconvert_all_kernel<<<(total + 255) / 256, 256, 0, stream>>>(
        dt_wqkv, dt_wo, dt_w1, dt_w2, lt_wqkv, lt_wo, lt_w1, lt_w2,
        conv_w, wt, cwt, rope);
  }

  build_feat_kernel<<<(ROWS1 * DIM + 255) / 256, 256, 0, stream>>>(x, cache, feat);
  ln_kernel<<<ROWS1 / 4, 256, 0, stream>>>(feat, h, dt_ln1_w, dt_ln1_b, ROWS1);

  // DT layer 0: w2 fuses DT layer-1 ln1 into h
  run_layer(feat, feat, h, qkh, vtb, attnb, ggb, wt + 0 * WT_SET, rope,
            ROWS1, N1, W_DT,
            dt_ln2_w, dt_ln2_b, dt_ln1_w + DIM, dt_ln1_b + DIM, nullptr, stream);
  // DT layer 1: w2 skips the fp32 store; writes bf16 result into h for the conv
  run_layer(feat, nullptr, h, qkh, vtb, attnb, ggb, wt + 1 * WT_SET, rope,
            ROWS1, N1, W_DT,
            dt_ln2_w + DIM, dt_ln2_b + DIM, nullptr, nullptr, h, stream);

  // conv as bf16 MFMA GEMM (K=256 over adjacent row pairs) + fused lt ln1 -> h2
  gemm_nln<<<dim3(1, ROWS2 / 64), 256, 0, stream>>>(h, 256, cwt, 256,
                                                    feat2, feat2, conv_b,
                                                    ROWS2, 256, 0,
                                                    lt_ln1_w, lt_ln1_b, h2, nullptr);

  // LT layer 0: w2 fuses LT layer-1 ln1 into h2
  run_layer(feat2, feat2, h2, qkh, vtb, attnb, ggb, wt + 2 * WT_SET, rope,
            ROWS2, N2, W_LT,
            lt_ln2_w, lt_ln2_b, lt_ln1_w + DIM, lt_ln1_b + DIM, nullptr, stream);
  // LT layer 1: final w2 writes d_out directly
  run_layer(feat2, outf, h2, qkh, vtb, attnb, ggb, wt + 3 * WT_SET, rope,
            ROWS2, N2, W_LT,
            lt_ln2_w + DIM, lt_ln2_b + DIM, nullptr, nullptr, nullptr, stream);
}

// Round 7
// 552.157 us; speedup vs baseline: 1.3513x; 1.3513x over previous
//
#include <hip/hip_runtime.h>
#include <cstdint>
#include <cstddef>

#define DIM    128
#define HEADS  6
#define INNER  192
#define QKV3   576
#define FFI    341
#define FF2    682
#define GGP    352   // padded K for w2 (341 -> 352)
#define BATCH  2
#define T_IN   12800
#define N1     12992 // 32 * 406
#define N2     6496  // 32 * 203
#define ROWS1  (BATCH * N1)  // 25984 = 64*406
#define ROWS2  (BATCH * N2)  // 12992 = 64*203
#define W_DT   406
#define W_LT   203

typedef unsigned short ushortT;
typedef unsigned int u32;
typedef __bf16 bf16x8 __attribute__((ext_vector_type(8)));
typedef float f32x4 __attribute__((ext_vector_type(4)));

__device__ __forceinline__ f32x4 mfma16(bf16x8 a, bf16x8 b, f32x4 c) {
  return __builtin_amdgcn_mfma_f32_16x16x32_bf16(a, b, c, 0, 0, 0);
}
__device__ __forceinline__ ushortT f2bf(float x) {
  union { __bf16 b; ushortT u; } c; c.b = (__bf16)x; return c.u;
}
__device__ __forceinline__ void async_copy16(const ushortT* g, ushortT* l) {
  __builtin_amdgcn_global_load_lds(
      (const __attribute__((address_space(1))) unsigned int*)g,
      (__attribute__((address_space(3))) unsigned int*)l, 16, 0, 0);
}

// ---------------- workspace layout (float units) ----------------
static constexpr size_t OF_FEAT = 0;                                    // f32 ROWS1*128
static constexpr size_t OF_H    = OF_FEAT + (size_t)ROWS1 * DIM;        // bf16 ROWS1*128
static constexpr size_t OF_QKH  = OF_H + (size_t)ROWS1 * DIM / 2;       // bf16 (ROWS1+128)*384
static constexpr size_t SZ_QKH  = ((size_t)(ROWS1 + 128) * 384) / 2;
static constexpr size_t OF_AO   = OF_QKH + SZ_QKH;                      // bf16 ROWS1*192
static constexpr size_t OF_VT   = OF_AO + (size_t)ROWS1 * INNER / 2;    // bf16 384*(N1+128)
static constexpr size_t SZ_VT   = ((size_t)384 * (N1 + 128)) / 2;
static constexpr size_t OF_GG   = OF_VT + SZ_VT;                        // bf16 ROWS1*352
static constexpr size_t OF_F2   = OF_GG + (size_t)ROWS1 * GGP / 2;      // f32 ROWS2*128
static constexpr size_t OF_WT   = OF_F2 + (size_t)ROWS2 * DIM;          // bf16 weights
static constexpr size_t WT_QKV = 0;        // 640*128
static constexpr size_t WT_WO  = 81920;    // 128*192
static constexpr size_t WT_W1  = 106496;   // 768*128 (interleaved a/gate)
static constexpr size_t WT_W2  = 204800;   // 128*352
static constexpr size_t WT_SET = 249856;   // ushorts per layer-set
static constexpr size_t OF_CW  = OF_WT + (4 * WT_SET) / 2 + 64;         // bf16 conv 128*256
static constexpr size_t OF_ROPE = OF_CW + (128 * 256) / 2 + 64;         // f32 N1*16 float2
static constexpr size_t OF_H2  = OF_ROPE + (size_t)N1 * 32;             // bf16 ROWS2*128

// ---------------- build feat ----------------
__global__ void build_feat_kernel(const float* __restrict__ x,
                                  const float* __restrict__ cache,
                                  float* __restrict__ feat) {
  int idx = blockIdx.x * 256 + threadIdx.x;
  if (idx >= ROWS1 * DIM) return;
  int d = idx & 127;
  int row = idx >> 7;
  int b = row / N1;
  int i = row - b * N1;
  int c = i / 406;
  int j = i - c * 406;
  float v;
  if (j < 6) v = cache[j * DIM + d];
  else       v = x[((size_t)b * DIM + d) * T_IN + (c * 400 + j - 6)];
  feat[idx] = v;
}

// ---------------- layernorm -> bf16 (standalone; 1 use remains) ----------------
__global__ __launch_bounds__(256) void ln_kernel(const float* __restrict__ x,
                                                 ushortT* __restrict__ y,
                                                 const float* __restrict__ w,
                                                 const float* __restrict__ bb,
                                                 int rows) {
  int row = blockIdx.x * 4 + (threadIdx.x >> 6);
  if (row >= rows) return;
  int lane = threadIdx.x & 63;
  const float* xr = x + (size_t)row * DIM;
  float2 v = *(const float2*)(xr + lane * 2);
  float s = v.x + v.y;
#pragma unroll
  for (int off = 32; off; off >>= 1) s += __shfl_xor(s, off);
  float mean = s * (1.0f / 128.0f);
  float dx = v.x - mean, dy = v.y - mean;
  float q = dx * dx + dy * dy;
#pragma unroll
  for (int off = 32; off; off >>= 1) q += __shfl_xor(q, off);
  float rstd = rsqrtf(q * (1.0f / 128.0f) + 1e-5f);
  float2 wv = *(const float2*)(w + lane * 2);
  float2 bv = *(const float2*)(bb + lane * 2);
  u32 packed = (u32)f2bf(dx * rstd * wv.x + bv.x) |
               ((u32)f2bf(dy * rstd * wv.y + bv.y) << 16);
  *(u32*)(y + (size_t)row * DIM + lane * 2) = packed;
}

// ---------------- bf16 GEMM 64xN128: residual + bias + fused LN + bf16 mirror ----------------
// Co (nullable) [M,128] = A @ Wt^T (+C, +bias). hout (nullable): LN of result.
// bfout (nullable): bf16 copy of result (pre-LN).
__global__ __launch_bounds__(256) void gemm_nln(
    const ushortT* __restrict__ A, int lda,
    const ushortT* __restrict__ Wt, int ldw,
    const float* __restrict__ C, float* __restrict__ Co,
    const float* __restrict__ bias,
    int M, int Kpad, int addC,
    const float* __restrict__ lnw, const float* __restrict__ lnb,
    ushortT* __restrict__ hout, ushortT* __restrict__ bfout) {
  __shared__ ushortT As[64 * 32];
  __shared__ ushortT Bs[128 * 32];
  __shared__ float lnS[64][4];           // [rowInBlock][half*2 + stat]
  const int tid = threadIdx.x;
  const int wid = tid >> 6, lane = tid & 63;
  const int ck = lane & 15, quad = lane >> 4;
  const int bm = blockIdx.y * 64;
  const int wr = (wid >> 1) * 32, wc = (wid & 1) * 64;
  const int half = wid & 1;
  f32x4 acc[2][4];
#pragma unroll
  for (int t = 0; t < 2; t++)
#pragma unroll
    for (int u = 0; u < 4; u++) acc[t][u] = (f32x4){0.f, 0.f, 0.f, 0.f};

  for (int k0 = 0; k0 < Kpad; k0 += 32) {
    __syncthreads();
    {
      int idx = wid * 64 + lane;
      int row = idx >> 2, seg = (idx & 3) << 3;
      async_copy16(A + (size_t)(bm + row) * lda + k0 + seg, As + (size_t)(wid * 64) * 8);
    }
#pragma unroll
    for (int c2 = 0; c2 < 2; c2++) {
      int idx = c2 * 256 + wid * 64 + lane;
      int row = idx >> 2, seg = (idx & 3) << 3;
      async_copy16(Wt + (size_t)row * ldw + k0 + seg, Bs + (size_t)(c2 * 256 + wid * 64) * 8);
    }
    __syncthreads();
    bf16x8 af[2], bfr[4];
#pragma unroll
    for (int t = 0; t < 2; t++)
      af[t] = *(const bf16x8*)&As[(wr + t * 16 + ck) * 32 + quad * 8];
#pragma unroll
    for (int u = 0; u < 4; u++)
      bfr[u] = *(const bf16x8*)&Bs[(wc + u * 16 + ck) * 32 + quad * 8];
#pragma unroll
    for (int t = 0; t < 2; t++)
#pragma unroll
      for (int u = 0; u < 4; u++)
        acc[t][u] = mfma16(af[t], bfr[u], acc[t][u]);
  }

  float bv4[4] = {0.f, 0.f, 0.f, 0.f};
  if (bias) {
#pragma unroll
    for (int u = 0; u < 4; u++) bv4[u] = bias[wc + u * 16 + ck];
  }
  float res[2][4][4];
#pragma unroll
  for (int t = 0; t < 2; t++) {
#pragma unroll
    for (int r = 0; r < 4; r++) {
      int row = bm + wr + t * 16 + quad * 4 + r;     // M % 64 == 0: always valid
      const float* crow = C + (size_t)row * DIM;
#pragma unroll
      for (int u = 0; u < 4; u++) {
        int col = wc + u * 16 + ck;
        float v = acc[t][u][r] + bv4[u];
        if (addC) v += crow[col];
        res[t][r][u] = v;
      }
      if (Co) {
        float* orow = Co + (size_t)row * DIM;
#pragma unroll
        for (int u = 0; u < 4; u++) orow[wc + u * 16 + ck] = res[t][r][u];
      }
      if (bfout) {
        ushortT* brow = bfout + (size_t)row * DIM;
#pragma unroll
        for (int u = 0; u < 4; u++) brow[wc + u * 16 + ck] = f2bf(res[t][r][u]);
      }
    }
  }

  if (hout) {
#pragma unroll
    for (int t = 0; t < 2; t++) {
#pragma unroll
      for (int r = 0; r < 4; r++) {
        float s1 = ((res[t][r][0] + res[t][r][1]) + (res[t][r][2] + res[t][r][3]));
        float s2 = ((res[t][r][0] * res[t][r][0] + res[t][r][1] * res[t][r][1]) +
                    (res[t][r][2] * res[t][r][2] + res[t][r][3] * res[t][r][3]));
        s1 += __shfl_xor(s1, 1); s2 += __shfl_xor(s2, 1);
        s1 += __shfl_xor(s1, 2); s2 += __shfl_xor(s2, 2);
        s1 += __shfl_xor(s1, 4); s2 += __shfl_xor(s2, 4);
        s1 += __shfl_xor(s1, 8); s2 += __shfl_xor(s2, 8);
        if (ck == 0) {
          int rowIn = wr + t * 16 + quad * 4 + r;
          lnS[rowIn][half * 2]     = s1;
          lnS[rowIn][half * 2 + 1] = s2;
        }
      }
    }
    __syncthreads();
    float lw[4], lb[4];
#pragma unroll
    for (int u = 0; u < 4; u++) {
      lw[u] = lnw[wc + u * 16 + ck];
      lb[u] = lnb[wc + u * 16 + ck];
    }
#pragma unroll
    for (int t = 0; t < 2; t++) {
#pragma unroll
      for (int r = 0; r < 4; r++) {
        int rowIn = wr + t * 16 + quad * 4 + r;
        float S1 = lnS[rowIn][0] + lnS[rowIn][2];
        float S2 = lnS[rowIn][1] + lnS[rowIn][3];
        float mean = S1 * (1.0f / 128.0f);
        float var = S2 * (1.0f / 128.0f) - mean * mean;
        float rstd = rsqrtf(var + 1e-5f);
        ushortT* hrow = hout + (size_t)(bm + rowIn) * DIM;
#pragma unroll
        for (int u = 0; u < 4; u++) {
          int col = wc + u * 16 + ck;
          hrow[col] = f2bf((res[t][r][u] - mean) * rstd * lw[u] + lb[u]);
        }
      }
    }
  }
}

// ---------------- fused qkv GEMM: rope(table) + bf16 + V-transpose epilogue ----------------
__global__ __launch_bounds__(256) void gemm_qkv(
    const ushortT* __restrict__ A,        // [M][128] bf16
    const ushortT* __restrict__ Wt,       // [640][128] bf16
    const float2* __restrict__ rope,      // [N1][16] (cos,sin)
    ushortT* __restrict__ qkh,            // [(M+128)][384]
    ushortT* __restrict__ vt,             // [384][nseqP]
    int M, int nseq, int nseqP) {
  __shared__ ushortT As[128 * 32];
  __shared__ ushortT Bs[128 * 32];
  const int tid = threadIdx.x;
  const int wid = tid >> 6, lane = tid & 63;
  const int ck = lane & 15, quad = lane >> 4;
  const int bm = blockIdx.y * 128, bn = blockIdx.x * 128;
  const int wr = (wid >> 1) * 64, wc = (wid & 1) * 64;
  f32x4 acc[4][4];
#pragma unroll
  for (int t = 0; t < 4; t++)
#pragma unroll
    for (int u = 0; u < 4; u++) acc[t][u] = (f32x4){0.f, 0.f, 0.f, 0.f};

  for (int k0 = 0; k0 < 128; k0 += 32) {
    __syncthreads();
#pragma unroll
    for (int c2 = 0; c2 < 2; c2++) {
      int idx = c2 * 256 + wid * 64 + lane;
      int row = idx >> 2, seg = (idx & 3) << 3;
      int ar = bm + row; if (ar > M - 1) ar = M - 1;
      async_copy16(A + (size_t)ar * 128 + k0 + seg, As + (size_t)(c2 * 256 + wid * 64) * 8);
      async_copy16(Wt + (size_t)(bn + row) * 128 + k0 + seg, Bs + (size_t)(c2 * 256 + wid * 64) * 8);
    }
    __syncthreads();
    bf16x8 af[4], bfr[4];
#pragma unroll
    for (int t = 0; t < 4; t++)
      af[t] = *(const bf16x8*)&As[(wr + t * 16 + ck) * 32 + quad * 8];
#pragma unroll
    for (int u = 0; u < 4; u++)
      bfr[u] = *(const bf16x8*)&Bs[(wc + u * 16 + ck) * 32 + quad * 8];
#pragma unroll
    for (int t = 0; t < 4; t++)
#pragma unroll
      for (int u = 0; u < 4; u++)
        acc[t][u] = mfma16(af[t], bfr[u], acc[t][u]);
  }

  const int s = bn + wc;
  if (s >= QKV3) return;

  if (s < 384) {
    const bool isQ = s < 192;
    const float SCq = 0.17677669529663687f * 1.4426950408889634f; // 32^-0.5 * log2e
#pragma unroll
    for (int t = 0; t < 4; t++) {
#pragma unroll
      for (int r = 0; r < 4; r++) {
        int row = bm + wr + t * 16 + quad * 4 + r;
        if (row >= M) continue;
        int pos = (row >= nseq) ? row - nseq : row;
        float2 cssn = rope[pos * 16 + ck];
        float cs = cssn.x, sn = cssn.y;
        ushortT* orow = qkh + (size_t)row * 384;
#pragma unroll
        for (int u = 0; u < 4; u += 2) {
          float a0 = acc[t][u][r], a1 = acc[t][u + 1][r];
          float o0 = a0 * cs - a1 * sn;
          float o1 = a1 * cs + a0 * sn;
          if (isQ) { o0 *= SCq; o1 *= SCq; }
          int c0 = s + u * 16 + ck;
          orow[c0]      = f2bf(o0);
          orow[c0 + 16] = f2bf(o1);
        }
      }
    }
  } else {
#pragma unroll
    for (int t = 0; t < 4; t++) {
      int rowb = bm + wr + t * 16 + quad * 4;
      if (rowb >= M) continue;
      int bb = (rowb >= nseq) ? 1 : 0;
      int posb = rowb - bb * nseq;
#pragma unroll
      for (int u = 0; u < 4; u++) {
        int cv = s - 384 + u * 16 + ck;
        int hh = cv >> 5, d = cv & 31;
        ushort4 o;
        o.x = f2bf(acc[t][u][0]);
        o.y = f2bf(acc[t][u][1]);
        o.z = f2bf(acc[t][u][2]);
        o.w = f2bf(acc[t][u][3]);
        *(ushort4*)(vt + ((size_t)((bb * 6 + hh) * 32 + d)) * nseqP + posb) = o;
      }
    }
  }
}

// ---------------- fused w1 GEMM + exact-GEGLU epilogue ----------------
__global__ __launch_bounds__(256) void gemm_w1g(
    const ushortT* __restrict__ A,
    const ushortT* __restrict__ Wt,       // [768][128] interleaved a/gate
    ushortT* __restrict__ gg,             // [M][GGP]
    int M) {
  __shared__ ushortT As[128 * 32];
  __shared__ ushortT Bs[128 * 32];
  const int tid = threadIdx.x;
  const int wid = tid >> 6, lane = tid & 63;
  const int ck = lane & 15, quad = lane >> 4;
  const int bm = blockIdx.y * 128, bn = blockIdx.x * 128;
  const int wr = (wid >> 1) * 64, wc = (wid & 1) * 64;
  f32x4 acc[4][4];
#pragma unroll
  for (int t = 0; t < 4; t++)
#pragma unroll
    for (int u = 0; u < 4; u++) acc[t][u] = (f32x4){0.f, 0.f, 0.f, 0.f};

  for (int k0 = 0; k0 < 128; k0 += 32) {
    __syncthreads();
#pragma unroll
    for (int c2 = 0; c2 < 2; c2++) {
      int idx = c2 * 256 + wid * 64 + lane;
      int row = idx >> 2, seg = (idx & 3) << 3;
      int ar = bm + row; if (ar > M - 1) ar = M - 1;
      async_copy16(A + (size_t)ar * 128 + k0 + seg, As + (size_t)(c2 * 256 + wid * 64) * 8);
      async_copy16(Wt + (size_t)(bn + row) * 128 + k0 + seg, Bs + (size_t)(c2 * 256 + wid * 64) * 8);
    }
    __syncthreads();
    bf16x8 af[4], bfr[4];
#pragma unroll
    for (int t = 0; t < 4; t++)
      af[t] = *(const bf16x8*)&As[(wr + t * 16 + ck) * 32 + quad * 8];
#pragma unroll
    for (int u = 0; u < 4; u++)
      bfr[u] = *(const bf16x8*)&Bs[(wc + u * 16 + ck) * 32 + quad * 8];
#pragma unroll
    for (int t = 0; t < 4; t++)
#pragma unroll
      for (int u = 0; u < 4; u++)
        acc[t][u] = mfma16(af[t], bfr[u], acc[t][u]);
  }

  const int s = bn + wc;
  if (s >= 704) return;
#pragma unroll
  for (int t = 0; t < 4; t++) {
#pragma unroll
    for (int r = 0; r < 4; r++) {
      int row = bm + wr + t * 16 + quad * 4 + r;
      if (row >= M) continue;
      ushortT* orow = gg + (size_t)row * GGP;
#pragma unroll
      for (int u = 0; u < 4; u += 2) {
        float a  = acc[t][u][r];
        float gt = acc[t][u + 1][r];
        float ge = 0.5f * gt * (1.0f + erff(gt * 0.70710678118654752f));
        int p = ((s + u * 16) >> 5) * 16 + ck;
        orow[p] = f2bf(a * ge);
      }
    }
  }
}

// ---------------- MFMA flash attention (R17 = R14 LDS structure + 2 Q-frags/wave:
//                  staged K/V tile + ds_reads shared by both fragments, 128 q/block,
//                  3-deep reg prefetch, in-register softmax, ones-MFMA l-sum,
//                  setprio(1) around the MFMA/softmax cluster) ----------------
__global__ __launch_bounds__(256) void attn_kernel(
    const ushortT* __restrict__ qkh, const ushortT* __restrict__ vt,
    ushortT* __restrict__ out, int nseq, int nseqP, int w, int nw, int qgroups) {
  __shared__ __align__(16) ushortT Ks[2][64 * 32]; // [buf][perm key rows][32 d], swizzled
  __shared__ __align__(16) ushortT Vs[2][32 * 64]; // [buf][32 d][64 keys],       swizzled

  const int bx = blockIdx.x;
  const int c = bx % nw;                    // chunk -> XCD affinity
  const int g = (qgroups - 1) - bx / nw;    // heaviest q-groups launch first
  const int h = blockIdx.y;
  const int b = blockIdx.z;
  const int tid = threadIdx.x;
  const int wv = tid >> 6;
  const int lane = tid & 63;
  const int ck = lane & 15;
  const int quad = lane >> 4;

  const ushortT* gq = qkh + (size_t)b * nseq * 384;
  const ushortT* gv = vt + ((size_t)(b * 6 + h) * 32) * nseqP;
  const int cw = c * w;
  const int q0 = g * 128;                  // 128 q-rows per block
  const int qt0 = q0 + wv * 16;            // fragment 0
  const int qt1 = q0 + 64 + wv * 16;       // fragment 1
  const bool f0on = qt0 < w;
  const bool f1on = qt1 < w;

  const int j0 = (c > 0) ? (c - 1) * w : 0;
  const int jend_block = cw + min(q0 + 127, w - 1) + 1;
  const int jf0 = f0on ? (cw + min(qt0 + 15, w - 1) + 1) : 0;
  const int jf1 = f1on ? (cw + min(qt1 + 15, w - 1) + 1) : 0;
  const int jmax = max(jf0, jf1);
  const int ntiles = (jend_block - j0 + 63) >> 6;

  bf16x8 qf0, qf1;   // Q[qt+ck][d = quad*8..+7] as MFMA B operand (clamped rows safe)
  {
    int qrow0 = cw + min(qt0 + ck, w - 1);
    qf0 = *(const bf16x8*)(gq + (size_t)qrow0 * 384 + h * 32 + quad * 8);
    int qrow1 = cw + min(qt1 + ck, w - 1);
    qf1 = *(const bf16x8*)(gq + (size_t)qrow1 * 384 + h * 32 + quad * 8);
  }

  // ---- staging addresses (setup-only) ----
  // K: thread stages logical key krow, d-chunk kch into permuted LDS row rho:
  // rho = 32*k5 + 16*k2 + 4*(k4k3) + (k1k0)  (bijective bit shuffle)
  const int krow = tid >> 2, kch = tid & 3;
  const int krho = ((krow >> 5) << 5) | (((krow >> 2) & 1) << 4) |
                   (((krow >> 3) & 3) << 2) | (krow & 3);
  const int kslot = krho * 4 + kch;
  const int kphys = kslot ^ ((kslot >> 3) & 7);
  const ushortT* ksrc = gq + (size_t)krow * 384 + 192 + h * 32 + kch * 8;
  // V: natural key order
  const int vphys = tid ^ ((tid >> 3) & 7);
  const ushortT* vsrc = gv + (size_t)(tid >> 3) * nseqP + (tid & 7) * 8;

  // ---- read addressing (halfword offsets into a 4KB buffer) ----
  const int kbase = ((4 * ck + quad) ^ (ck >> 1)) * 8;
  const int p0 = ((8 * ck + quad) ^ (ck & 7)) * 8;
  const int p1 = p0 ^ 32;   // (8ck+quad+4): +4 == ^bit2 of slot == ^32 halfwords

  f32x4 olo0 = {0.f, 0.f, 0.f, 0.f}, ohi0 = {0.f, 0.f, 0.f, 0.f}, accl0 = {0.f, 0.f, 0.f, 0.f};
  f32x4 olo1 = {0.f, 0.f, 0.f, 0.f}, ohi1 = {0.f, 0.f, 0.f, 0.f}, accl1 = {0.f, 0.f, 0.f, 0.f};
  bf16x8 onesf;
  {
    union { u32 u[4]; bf16x8 v; } o_;
    o_.u[0] = o_.u[1] = o_.u[2] = o_.u[3] = 0x3F803F80u;  // bf16(1.0) x2
    onesf = o_.v;
  }

  auto tileoff = [&](int t) -> int { return j0 + 64 * min(t, ntiles - 1); };

  // prologue: tile0 -> buf0 directly; X <- tile1, Y <- tile2 (clamped)
  float4 kX, vX, kY, vY;
  {
    float4 k0 = *(const float4*)(ksrc + (size_t)j0 * 384);
    float4 v0 = *(const float4*)(vsrc + j0);
    *(float4*)&Ks[0][(size_t)kphys * 8] = k0;
    *(float4*)&Vs[0][(size_t)vphys * 8] = v0;
    kX = *(const float4*)(ksrc + (size_t)tileoff(1) * 384);
    vX = *(const float4*)(vsrc + tileoff(1));
    kY = *(const float4*)(ksrc + (size_t)tileoff(2) * 384);
    vY = *(const float4*)(vsrc + tileoff(2));
  }

  // per-fragment softmax+PV, reusing the tile's K/V fragments
  auto frag = [&](int tb, const bf16x8& qf, int qt,
                  const bf16x8& kf0, const bf16x8& kf1, const bf16x8& kf2, const bf16x8& kf3,
                  const bf16x8& vlo0, const bf16x8& vlo1, const bf16x8& vhi0, const bf16x8& vhi1,
                  f32x4& olo, f32x4& ohi, f32x4& accl) {
    f32x4 z = {0.f, 0.f, 0.f, 0.f};
    f32x4 s0 = mfma16(kf0, qf, z);   // D[perm-key][q]: lane holds q=qt+ck
    f32x4 s1 = mfma16(kf1, qf, z);
    f32x4 s2 = mfma16(kf2, qf, z);
    f32x4 s3 = mfma16(kf3, qf, z);
    // score (t,r): logical key = tb + 32*(t>>1) + 4*(t&1) + 8*quad + r
    if (tb + 63 > cw + qt) {
      int q = cw + qt + ck;
      int kb = tb + 8 * quad;
#pragma unroll
      for (int r = 0; r < 4; r++) {
        if (kb + r > q)      s0[r] = -__builtin_inff();
        if (kb + 4 + r > q)  s1[r] = -__builtin_inff();
        if (kb + 32 + r > q) s2[r] = -__builtin_inff();
        if (kb + 36 + r > q) s3[r] = -__builtin_inff();
      }
    }
    float e00 = exp2f(s0[0]), e01 = exp2f(s0[1]), e02 = exp2f(s0[2]), e03 = exp2f(s0[3]);
    float e10 = exp2f(s1[0]), e11 = exp2f(s1[1]), e12 = exp2f(s1[2]), e13 = exp2f(s1[3]);
    float e20 = exp2f(s2[0]), e21 = exp2f(s2[1]), e22 = exp2f(s2[2]), e23 = exp2f(s2[3]);
    float e30 = exp2f(s3[0]), e31 = exp2f(s3[1]), e32 = exp2f(s3[2]), e33 = exp2f(s3[3]);
    union { bf16x8 v; u32 u[4]; } pa0, pa1;
    pa0.u[0] = (u32)f2bf(e00) | ((u32)f2bf(e01) << 16);
    pa0.u[1] = (u32)f2bf(e02) | ((u32)f2bf(e03) << 16);
    pa0.u[2] = (u32)f2bf(e10) | ((u32)f2bf(e11) << 16);
    pa0.u[3] = (u32)f2bf(e12) | ((u32)f2bf(e13) << 16);
    pa1.u[0] = (u32)f2bf(e20) | ((u32)f2bf(e21) << 16);
    pa1.u[1] = (u32)f2bf(e22) | ((u32)f2bf(e23) << 16);
    pa1.u[2] = (u32)f2bf(e30) | ((u32)f2bf(e31) << 16);
    pa1.u[3] = (u32)f2bf(e32) | ((u32)f2bf(e33) << 16);
    olo  = mfma16(pa0.v, vlo0, olo);
    olo  = mfma16(pa1.v, vlo1, olo);
    ohi  = mfma16(pa0.v, vhi0, ohi);
    ohi  = mfma16(pa1.v, vhi1, ohi);
    accl = mfma16(pa0.v, onesf, accl);   // row-sum on the MFMA pipe
    accl = mfma16(pa1.v, onesf, accl);
  };

  auto compute = [&](const ushortT* KsB, const ushortT* VsB, int tb) {
    if (tb >= jmax) return;
    __builtin_amdgcn_s_setprio(1);
    bf16x8 kf0 = *(const bf16x8*)&KsB[kbase];
    bf16x8 kf1 = *(const bf16x8*)&KsB[kbase + 512];
    bf16x8 kf2 = *(const bf16x8*)&KsB[kbase + 1024];
    bf16x8 kf3 = *(const bf16x8*)&KsB[kbase + 1536];
    bf16x8 vlo0 = *(const bf16x8*)&VsB[p0];
    bf16x8 vlo1 = *(const bf16x8*)&VsB[p1];
    bf16x8 vhi0 = *(const bf16x8*)&VsB[p0 + 1024];
    bf16x8 vhi1 = *(const bf16x8*)&VsB[p1 + 1024];
    if (tb < jf0)
      frag(tb, qf0, qt0, kf0, kf1, kf2, kf3, vlo0, vlo1, vhi0, vhi1, olo0, ohi0, accl0);
    if (tb < jf1)
      frag(tb, qf1, qt1, kf0, kf1, kf2, kf3, vlo0, vlo1, vhi0, vhi1, olo1, ohi1, accl1);
    __builtin_amdgcn_s_setprio(0);
  };

  // main loop, unrolled x2: reg set X serves odd-buf writes, Y even-buf writes.
  // A load issued at tile i is consumed (ds_write) at tile i+2 -> ~2-tile vmcnt slack.
  for (int i = 0; i < ntiles; i += 2) {
    __syncthreads();                       // even tile i: buf0 ready for reads
    *(float4*)&Ks[1][(size_t)kphys * 8] = kX;      // tile i+1 -> buf1
    *(float4*)&Vs[1][(size_t)vphys * 8] = vX;
    kX = *(const float4*)(ksrc + (size_t)tileoff(i + 3) * 384);
    vX = *(const float4*)(vsrc + tileoff(i + 3));
    compute(Ks[0], Vs[0], j0 + i * 64);

    __syncthreads();                       // odd tile i+1: buf1 ready for reads
    *(float4*)&Ks[0][(size_t)kphys * 8] = kY;      // tile i+2 -> buf0
    *(float4*)&Vs[0][(size_t)vphys * 8] = vY;
    kY = *(const float4*)(ksrc + (size_t)tileoff(i + 4) * 384);
    vY = *(const float4*)(vsrc + tileoff(i + 4));
    compute(Ks[1], Vs[1], j0 + (i + 1) * 64);
  }

  // epilogue: accl[r] is l for q = qt+quad*4+r (same layout as olo/ohi) -> no shuffles
  if (f0on) {
#pragma unroll
    for (int r = 0; r < 4; r++) {
      int qi = qt0 + quad * 4 + r;
      if (qi < w) {
        float invr = 1.0f / accl0[r];
        ushortT* orow = out + ((size_t)b * nseq + cw + qi) * INNER + h * 32;
        orow[ck]      = f2bf(olo0[r] * invr);
        orow[ck + 16] = f2bf(ohi0[r] * invr);
      }
    }
  }
  if (f1on) {
#pragma unroll
    for (int r = 0; r < 4; r++) {
      int qi = qt1 + quad * 4 + r;
      if (qi < w) {
        float invr = 1.0f / accl1[r];
        ushortT* orow = out + ((size_t)b * nseq + cw + qi) * INNER + h * 32;
        orow[ck]      = f2bf(olo1[r] * invr);
        orow[ck + 16] = f2bf(ohi1[r] * invr);
      }
    }
  }
}

// ---------------- merged setup: weights + conv bf16 + rope table ----------------
__global__ void wconvert_all_kernel(
    const float* __restrict__ dq, const float* __restrict__ dwo,
    const float* __restrict__ dw1, const float* __restrict__ dw2,
    const float* __restrict__ lq, const float* __restrict__ lwo,
    const float* __restrict__ lw1, const float* __restrict__ lw2,
    const float* __restrict__ convw,
    ushortT* __restrict__ wt, ushortT* __restrict__ cwt,
    float2* __restrict__ rope) {
  int idx = blockIdx.x * 256 + threadIdx.x;
  const int TOTW = 4 * (int)WT_SET;
  const int CWN = 128 * 256;
  if (idx < TOTW) {
    int s = idx / (int)WT_SET;
    int rem = idx - s * (int)WT_SET;
    int lyr = s & 1;
    const float* Wq = ((s < 2) ? dq : lq) + (size_t)lyr * DIM * QKV3;
    const float* Wo = ((s < 2) ? dwo : lwo) + (size_t)lyr * INNER * DIM;
    const float* W1 = ((s < 2) ? dw1 : lw1) + (size_t)lyr * DIM * FF2;
    const float* W2 = ((s < 2) ? dw2 : lw2) + (size_t)lyr * FFI * DIM;
    float v = 0.f;
    if (rem < (int)WT_WO) {                 // qkv: [640][128]
      int n = rem >> 7, k = rem & 127;
      if (n < QKV3) v = Wq[(size_t)k * QKV3 + n];
    } else if (rem < (int)WT_W1) {          // wo: [128][192]
      int r = rem - (int)WT_WO;
      int n = r / INNER, k = r - n * INNER;
      v = Wo[(size_t)k * DIM + n];
    } else if (rem < (int)WT_W2) {          // w1 interleaved: [768][128]
      int r = rem - (int)WT_W1;
      int n = r >> 7, k = r & 127;
      if (n < 704) {
        int blk = n >> 5, wi = n & 31;
        int p = blk * 16 + (wi & 15);
        if (p < FFI) {
          int src = (wi < 16) ? p : FFI + p;
          v = W1[(size_t)k * FF2 + src];
        }
      }
    } else {                                // w2: [128][352]
      int r = rem - (int)WT_W2;
      int n = r / GGP, k = r - n * GGP;
      if (k < FFI) v = W2[(size_t)k * DIM + n];
    }
    wt[idx] = f2bf(v);
  } else if (idx < TOTW + CWN) {
    // conv weights -> bf16 transposed: cwt[o][kk*128+i] = convw[(o*128+i)*2+kk]
    int r = idx - TOTW;
    int o = r >> 8, k = r & 255;
    int kk = k >> 7, i = k & 127;
    cwt[r] = f2bf(convw[((size_t)o * DIM + i) * 2 + kk]);
  } else {
    int r = idx - TOTW - CWN;
    if (r < N1 * 16) {
      int pos = r >> 4, k = r & 15;
      float invf = 1.0f / powf(10000.0f, (float)k * (1.0f / 16.0f));
      float sn, cs;
      sincosf((float)pos * invf, &sn, &cs);
      rope[r] = make_float2(cs, sn);
    }
  }
}

// ---------------- host-side layer driver ----------------
// hbuf = this layer's LN1 input activations (bf16). wo fuses ln2 -> hbuf;
// w2 fuses next-layer ln1 -> hbuf (if nlnw) and/or writes bf16 mirror (w2bf).
static void run_layer(float* F, float* Fout, ushortT* hbuf, ushortT* qkh, ushortT* vtb,
                      ushortT* attnb, ushortT* ggb, const ushortT* wt,
                      const float2* rope,
                      int M, int nseq, int w,
                      const float* ln2w, const float* ln2b,
                      const float* nlnw, const float* nlnb,
                      ushortT* w2bf, hipStream_t stream) {
  int nseqP = nseq + 128;
  int gy = (M + 127) / 128;
  int gy64 = M / 64;
  gemm_qkv<<<dim3(5, gy), 256, 0, stream>>>(hbuf, wt + WT_QKV, rope, qkh, vtb, M, nseq, nseqP);
  int nw = nseq / w;
  int qgroups = (w + 127) / 128;           // 128 q-rows per block (2 frags/wave)
  attn_kernel<<<dim3(nw * qgroups, HEADS, BATCH), 256, 0, stream>>>(qkh, vtb, attnb,
                                                                    nseq, nseqP, w, nw, qgroups);
  gemm_nln<<<dim3(1, gy64), 256, 0, stream>>>(attnb, INNER, wt + WT_WO, INNER, F, F,
                                              nullptr, M, INNER, 1, ln2w, ln2b,
                                              hbuf, nullptr);
  gemm_w1g<<<dim3(6, gy), 256, 0, stream>>>(hbuf, wt + WT_W1, ggb, M);
  gemm_nln<<<dim3(1, gy64), 256, 0, stream>>>(ggb, GGP, wt + WT_W2, GGP, F, Fout,
                                              nullptr, M, GGP, 1, nlnw, nlnb,
                                              nlnw ? hbuf : (ushortT*)nullptr, w2bf);
}

extern "C" void kernel_launch(void* const* d_in, const int* in_sizes, int n_in,
                              void* d_out, int out_size, void* d_ws, size_t ws_size,
                              hipStream_t stream) {
  const float* x        = (const float*)d_in[0];
  const float* cache    = (const float*)d_in[1];
  const float* dt_ln1_w = (const float*)d_in[2];
  const float* dt_ln1_b = (const float*)d_in[3];
  const float* dt_wqkv  = (const float*)d_in[4];
  const float* dt_wo    = (const float*)d_in[5];
  const float* dt_ln2_w = (const float*)d_in[6];
  const float* dt_ln2_b = (const float*)d_in[7];
  const float* dt_w1    = (const float*)d_in[8];
  const float* dt_w2    = (const float*)d_in[9];
  const float* lt_ln1_w = (const float*)d_in[10];
  const float* lt_ln1_b = (const float*)d_in[11];
  const float* lt_wqkv  = (const float*)d_in[12];
  const float* lt_wo    = (const float*)d_in[13];
  const float* lt_ln2_w = (const float*)d_in[14];
  const float* lt_ln2_b = (const float*)d_in[15];
  const float* lt_w1    = (const float*)d_in[16];
  const float* lt_w2    = (const float*)d_in[17];
  const float* conv_w   = (const float*)d_in[18];
  const float* conv_b   = (const float*)d_in[19];

  float* ws     = (float*)d_ws;
  float* feat   = ws + OF_FEAT;
  ushortT* h    = (ushortT*)(ws + OF_H);
  ushortT* qkh  = (ushortT*)(ws + OF_QKH);
  ushortT* attnb= (ushortT*)(ws + OF_AO);
  ushortT* vtb  = (ushortT*)(ws + OF_VT);
  ushortT* ggb  = (ushortT*)(ws + OF_GG);
  float* feat2  = ws + OF_F2;
  ushortT* wt   = (ushortT*)(ws + OF_WT);
  ushortT* cwt  = (ushortT*)(ws + OF_CW);
  float2* rope  = (float2*)(ws + OF_ROPE);
  ushortT* h2   = (ushortT*)(ws + OF_H2);
  float* outf   = (float*)d_out;

  {
    int total = 4 * (int)WT_SET + 128 * 256 + N1 * 16;
    wconvert_all_kernel<<<(total + 255) / 256, 256, 0, stream>>>(
        dt_wqkv, dt_wo, dt_w1, dt_w2, lt_wqkv, lt_wo, lt_w1, lt_w2,
        conv_w, wt, cwt, rope);
  }

  build_feat_kernel<<<(ROWS1 * DIM + 255) / 256, 256, 0, stream>>>(x, cache, feat);
  ln_kernel<<<ROWS1 / 4, 256, 0, stream>>>(feat, h, dt_ln1_w, dt_ln1_b, ROWS1);

  // DT layer 0: w2 fuses DT layer-1 ln1 into h
  run_layer(feat, feat, h, qkh, vtb, attnb, ggb, wt + 0 * WT_SET, rope,
            ROWS1, N1, W_DT,
            dt_ln2_w, dt_ln2_b, dt_ln1_w + DIM, dt_ln1_b + DIM, nullptr, stream);
  // DT layer 1: w2 skips the fp32 store; writes bf16 result into h for the conv
  run_layer(feat, nullptr, h, qkh, vtb, attnb, ggb, wt + 1 * WT_SET, rope,
            ROWS1, N1, W_DT,
            dt_ln2_w + DIM, dt_ln2_b + DIM, nullptr, nullptr, h, stream);

  // conv as bf16 MFMA GEMM (K=256 over adjacent row pairs) + fused lt ln1 -> h2
  gemm_nln<<<dim3(1, ROWS2 / 64), 256, 0, stream>>>(h, 256, cwt, 256,
                                                    feat2, feat2, conv_b,
                                                    ROWS2, 256, 0,
                                                    lt_ln1_w, lt_ln1_b, h2, nullptr);

  // LT layer 0: w2 fuses LT layer-1 ln1 into h2
  run_layer(feat2, feat2, h2, qkh, vtb, attnb, ggb, wt + 2 * WT_SET, rope,
            ROWS2, N2, W_LT,
            lt_ln2_w, lt_ln2_b, lt_ln1_w + DIM, lt_ln1_b + DIM, nullptr, stream);
  // LT layer 1: final w2 writes d_out directly
  run_layer(feat2, outf, h2, qkh, vtb, attnb, ggb, wt + 3 * WT_SET, rope,
            ROWS2, N2, W_LT,
            lt_ln2_w + DIM, lt_ln2_b + DIM, nullptr, nullptr, nullptr, stream);
}

// Round 8
// 541.170 us; speedup vs baseline: 1.3787x; 1.0203x over previous
//
#include <hip/hip_runtime.h>
#include <cstdint>
#include <cstddef>

#define DIM    128
#define HEADS  6
#define INNER  192
#define QKV3   576
#define FFI    341
#define FF2    682
#define GGP    352   // padded K for w2 (341 -> 352)
#define BATCH  2
#define T_IN   12800
#define N1     12992 // 32 * 406
#define N2     6496  // 32 * 203
#define ROWS1  (BATCH * N1)  // 25984 = 64*406
#define ROWS2  (BATCH * N2)  // 12992 = 64*203
#define W_DT   406
#define W_LT   203

typedef unsigned short ushortT;
typedef unsigned int u32;
typedef __bf16 bf16x8 __attribute__((ext_vector_type(8)));
typedef float f32x4 __attribute__((ext_vector_type(4)));

__device__ __forceinline__ f32x4 mfma16(bf16x8 a, bf16x8 b, f32x4 c) {
  return __builtin_amdgcn_mfma_f32_16x16x32_bf16(a, b, c, 0, 0, 0);
}
__device__ __forceinline__ ushortT f2bf(float x) {
  union { __bf16 b; ushortT u; } c; c.b = (__bf16)x; return c.u;
}
__device__ __forceinline__ void async_copy16(const ushortT* g, ushortT* l) {
  __builtin_amdgcn_global_load_lds(
      (const __attribute__((address_space(1))) unsigned int*)g,
      (__attribute__((address_space(3))) unsigned int*)l, 16, 0, 0);
}

// ---------------- workspace layout (float units) ----------------
static constexpr size_t OF_FEAT = 0;                                    // f32 ROWS1*128
static constexpr size_t OF_H    = OF_FEAT + (size_t)ROWS1 * DIM;        // bf16 ROWS1*128
static constexpr size_t OF_QKH  = OF_H + (size_t)ROWS1 * DIM / 2;       // bf16 (ROWS1+128)*384
static constexpr size_t SZ_QKH  = ((size_t)(ROWS1 + 128) * 384) / 2;
static constexpr size_t OF_AO   = OF_QKH + SZ_QKH;                      // bf16 ROWS1*192
static constexpr size_t OF_VT   = OF_AO + (size_t)ROWS1 * INNER / 2;    // bf16 384*(N1+128)
static constexpr size_t SZ_VT   = ((size_t)384 * (N1 + 128)) / 2;
static constexpr size_t OF_GG   = OF_VT + SZ_VT;                        // bf16 ROWS1*352
static constexpr size_t OF_F2   = OF_GG + (size_t)ROWS1 * GGP / 2;      // f32 ROWS2*128
static constexpr size_t OF_WT   = OF_F2 + (size_t)ROWS2 * DIM;          // bf16 weights
static constexpr size_t WT_QKV = 0;        // 640*128
static constexpr size_t WT_WO  = 81920;    // 128*192
static constexpr size_t WT_W1  = 106496;   // 768*128 (interleaved a/gate)
static constexpr size_t WT_W2  = 204800;   // 128*352
static constexpr size_t WT_SET = 249856;   // ushorts per layer-set
static constexpr size_t OF_CW  = OF_WT + (4 * WT_SET) / 2 + 64;         // bf16 conv 128*256
static constexpr size_t OF_ROPE = OF_CW + (128 * 256) / 2 + 64;         // f32 N1*16 float2
static constexpr size_t OF_H2  = OF_ROPE + (size_t)N1 * 32;             // bf16 ROWS2*128

// ---------------- build feat ----------------
__global__ void build_feat_kernel(const float* __restrict__ x,
                                  const float* __restrict__ cache,
                                  float* __restrict__ feat) {
  int idx = blockIdx.x * 256 + threadIdx.x;
  if (idx >= ROWS1 * DIM) return;
  int d = idx & 127;
  int row = idx >> 7;
  int b = row / N1;
  int i = row - b * N1;
  int c = i / 406;
  int j = i - c * 406;
  float v;
  if (j < 6) v = cache[j * DIM + d];
  else       v = x[((size_t)b * DIM + d) * T_IN + (c * 400 + j - 6)];
  feat[idx] = v;
}

// ---------------- layernorm -> bf16 (standalone; 1 use remains) ----------------
__global__ __launch_bounds__(256) void ln_kernel(const float* __restrict__ x,
                                                 ushortT* __restrict__ y,
                                                 const float* __restrict__ w,
                                                 const float* __restrict__ bb,
                                                 int rows) {
  int row = blockIdx.x * 4 + (threadIdx.x >> 6);
  if (row >= rows) return;
  int lane = threadIdx.x & 63;
  const float* xr = x + (size_t)row * DIM;
  float2 v = *(const float2*)(xr + lane * 2);
  float s = v.x + v.y;
#pragma unroll
  for (int off = 32; off; off >>= 1) s += __shfl_xor(s, off);
  float mean = s * (1.0f / 128.0f);
  float dx = v.x - mean, dy = v.y - mean;
  float q = dx * dx + dy * dy;
#pragma unroll
  for (int off = 32; off; off >>= 1) q += __shfl_xor(q, off);
  float rstd = rsqrtf(q * (1.0f / 128.0f) + 1e-5f);
  float2 wv = *(const float2*)(w + lane * 2);
  float2 bv = *(const float2*)(bb + lane * 2);
  u32 packed = (u32)f2bf(dx * rstd * wv.x + bv.x) |
               ((u32)f2bf(dy * rstd * wv.y + bv.y) << 16);
  *(u32*)(y + (size_t)row * DIM + lane * 2) = packed;
}

// ---------------- bf16 GEMM 64xN128: dbuf K-steps (stage t+1 under compute t),
//                  residual + bias + fused LN + bf16 mirror ----------------
__global__ __launch_bounds__(256) void gemm_nln(
    const ushortT* __restrict__ A, int lda,
    const ushortT* __restrict__ Wt, int ldw,
    const float* __restrict__ C, float* __restrict__ Co,
    const float* __restrict__ bias,
    int M, int Kpad, int addC,
    const float* __restrict__ lnw, const float* __restrict__ lnb,
    ushortT* __restrict__ hout, ushortT* __restrict__ bfout) {
  __shared__ ushortT As[2][64 * 32];
  __shared__ ushortT Bs[2][128 * 32];
  __shared__ float lnS[64][4];           // [rowInBlock][half*2 + stat]
  const int tid = threadIdx.x;
  const int wid = tid >> 6, lane = tid & 63;
  const int ck = lane & 15, quad = lane >> 4;
  const int bm = blockIdx.y * 64;
  const int wr = (wid >> 1) * 32, wc = (wid & 1) * 64;
  const int half = wid & 1;
  f32x4 acc[2][4];
#pragma unroll
  for (int t = 0; t < 2; t++)
#pragma unroll
    for (int u = 0; u < 4; u++) acc[t][u] = (f32x4){0.f, 0.f, 0.f, 0.f};

  auto stage = [&](int bsel, int k0) {
    {
      int idx = wid * 64 + lane;
      int row = idx >> 2, seg = (idx & 3) << 3;
      async_copy16(A + (size_t)(bm + row) * lda + k0 + seg,
                   As[bsel] + (size_t)(wid * 64) * 8);
    }
#pragma unroll
    for (int c2 = 0; c2 < 2; c2++) {
      int idx = c2 * 256 + wid * 64 + lane;
      int row = idx >> 2, seg = (idx & 3) << 3;
      async_copy16(Wt + (size_t)row * ldw + k0 + seg,
                   Bs[bsel] + (size_t)(c2 * 256 + wid * 64) * 8);
    }
  };

  stage(0, 0);
  __syncthreads();
  const int nt = Kpad >> 5;
  for (int t = 0; t < nt; t++) {
    const int cur = t & 1;
    if (t + 1 < nt) stage(cur ^ 1, (t + 1) << 5);
    bf16x8 af[2], bfr[4];
#pragma unroll
    for (int tt = 0; tt < 2; tt++)
      af[tt] = *(const bf16x8*)&As[cur][(wr + tt * 16 + ck) * 32 + quad * 8];
#pragma unroll
    for (int u = 0; u < 4; u++)
      bfr[u] = *(const bf16x8*)&Bs[cur][(wc + u * 16 + ck) * 32 + quad * 8];
#pragma unroll
    for (int tt = 0; tt < 2; tt++)
#pragma unroll
      for (int u = 0; u < 4; u++)
        acc[tt][u] = mfma16(af[tt], bfr[u], acc[tt][u]);
    __syncthreads();
  }

  float bv4[4] = {0.f, 0.f, 0.f, 0.f};
  if (bias) {
#pragma unroll
    for (int u = 0; u < 4; u++) bv4[u] = bias[wc + u * 16 + ck];
  }
  float res[2][4][4];
#pragma unroll
  for (int t = 0; t < 2; t++) {
#pragma unroll
    for (int r = 0; r < 4; r++) {
      int row = bm + wr + t * 16 + quad * 4 + r;     // M % 64 == 0: always valid
      const float* crow = C + (size_t)row * DIM;
#pragma unroll
      for (int u = 0; u < 4; u++) {
        int col = wc + u * 16 + ck;
        float v = acc[t][u][r] + bv4[u];
        if (addC) v += crow[col];
        res[t][r][u] = v;
      }
      if (Co) {
        float* orow = Co + (size_t)row * DIM;
#pragma unroll
        for (int u = 0; u < 4; u++) orow[wc + u * 16 + ck] = res[t][r][u];
      }
      if (bfout) {
        ushortT* brow = bfout + (size_t)row * DIM;
#pragma unroll
        for (int u = 0; u < 4; u++) brow[wc + u * 16 + ck] = f2bf(res[t][r][u]);
      }
    }
  }

  if (hout) {
#pragma unroll
    for (int t = 0; t < 2; t++) {
#pragma unroll
      for (int r = 0; r < 4; r++) {
        float s1 = ((res[t][r][0] + res[t][r][1]) + (res[t][r][2] + res[t][r][3]));
        float s2 = ((res[t][r][0] * res[t][r][0] + res[t][r][1] * res[t][r][1]) +
                    (res[t][r][2] * res[t][r][2] + res[t][r][3] * res[t][r][3]));
        s1 += __shfl_xor(s1, 1); s2 += __shfl_xor(s2, 1);
        s1 += __shfl_xor(s1, 2); s2 += __shfl_xor(s2, 2);
        s1 += __shfl_xor(s1, 4); s2 += __shfl_xor(s2, 4);
        s1 += __shfl_xor(s1, 8); s2 += __shfl_xor(s2, 8);
        if (ck == 0) {
          int rowIn = wr + t * 16 + quad * 4 + r;
          lnS[rowIn][half * 2]     = s1;
          lnS[rowIn][half * 2 + 1] = s2;
        }
      }
    }
    __syncthreads();
    float lw[4], lb[4];
#pragma unroll
    for (int u = 0; u < 4; u++) {
      lw[u] = lnw[wc + u * 16 + ck];
      lb[u] = lnb[wc + u * 16 + ck];
    }
#pragma unroll
    for (int t = 0; t < 2; t++) {
#pragma unroll
      for (int r = 0; r < 4; r++) {
        int rowIn = wr + t * 16 + quad * 4 + r;
        float S1 = lnS[rowIn][0] + lnS[rowIn][2];
        float S2 = lnS[rowIn][1] + lnS[rowIn][3];
        float mean = S1 * (1.0f / 128.0f);
        float var = S2 * (1.0f / 128.0f) - mean * mean;
        float rstd = rsqrtf(var + 1e-5f);
        ushortT* hrow = hout + (size_t)(bm + rowIn) * DIM;
#pragma unroll
        for (int u = 0; u < 4; u++) {
          int col = wc + u * 16 + ck;
          hrow[col] = f2bf((res[t][r][u] - mean) * rstd * lw[u] + lb[u]);
        }
      }
    }
  }
}

// ---------------- fused qkv GEMM (dbuf K-steps): rope + bf16 + V-transpose ----------------
__global__ __launch_bounds__(256) void gemm_qkv(
    const ushortT* __restrict__ A,        // [M][128] bf16
    const ushortT* __restrict__ Wt,       // [640][128] bf16
    const float2* __restrict__ rope,      // [N1][16] (cos,sin)
    ushortT* __restrict__ qkh,            // [(M+128)][384]
    ushortT* __restrict__ vt,             // [384][nseqP]
    int M, int nseq, int nseqP) {
  __shared__ ushortT As[2][128 * 32];
  __shared__ ushortT Bs[2][128 * 32];
  const int tid = threadIdx.x;
  const int wid = tid >> 6, lane = tid & 63;
  const int ck = lane & 15, quad = lane >> 4;
  const int bm = blockIdx.y * 128, bn = blockIdx.x * 128;
  const int wr = (wid >> 1) * 64, wc = (wid & 1) * 64;
  f32x4 acc[4][4];
#pragma unroll
  for (int t = 0; t < 4; t++)
#pragma unroll
    for (int u = 0; u < 4; u++) acc[t][u] = (f32x4){0.f, 0.f, 0.f, 0.f};

  auto stage = [&](int bsel, int k0) {
#pragma unroll
    for (int c2 = 0; c2 < 2; c2++) {
      int idx = c2 * 256 + wid * 64 + lane;
      int row = idx >> 2, seg = (idx & 3) << 3;
      int ar = bm + row; if (ar > M - 1) ar = M - 1;
      async_copy16(A + (size_t)ar * 128 + k0 + seg,
                   As[bsel] + (size_t)(c2 * 256 + wid * 64) * 8);
      async_copy16(Wt + (size_t)(bn + row) * 128 + k0 + seg,
                   Bs[bsel] + (size_t)(c2 * 256 + wid * 64) * 8);
    }
  };

  stage(0, 0);
  __syncthreads();
  for (int t = 0; t < 4; t++) {
    const int cur = t & 1;
    if (t < 3) stage(cur ^ 1, (t + 1) * 32);
    bf16x8 af[4], bfr[4];
#pragma unroll
    for (int tt = 0; tt < 4; tt++)
      af[tt] = *(const bf16x8*)&As[cur][(wr + tt * 16 + ck) * 32 + quad * 8];
#pragma unroll
    for (int u = 0; u < 4; u++)
      bfr[u] = *(const bf16x8*)&Bs[cur][(wc + u * 16 + ck) * 32 + quad * 8];
#pragma unroll
    for (int tt = 0; tt < 4; tt++)
#pragma unroll
      for (int u = 0; u < 4; u++)
        acc[tt][u] = mfma16(af[tt], bfr[u], acc[tt][u]);
    __syncthreads();
  }

  const int s = bn + wc;
  if (s >= QKV3) return;

  if (s < 384) {
    const bool isQ = s < 192;
    const float SCq = 0.17677669529663687f * 1.4426950408889634f; // 32^-0.5 * log2e
#pragma unroll
    for (int t = 0; t < 4; t++) {
#pragma unroll
      for (int r = 0; r < 4; r++) {
        int row = bm + wr + t * 16 + quad * 4 + r;
        if (row >= M) continue;
        int pos = (row >= nseq) ? row - nseq : row;
        float2 cssn = rope[pos * 16 + ck];
        float cs = cssn.x, sn = cssn.y;
        ushortT* orow = qkh + (size_t)row * 384;
#pragma unroll
        for (int u = 0; u < 4; u += 2) {
          float a0 = acc[t][u][r], a1 = acc[t][u + 1][r];
          float o0 = a0 * cs - a1 * sn;
          float o1 = a1 * cs + a0 * sn;
          if (isQ) { o0 *= SCq; o1 *= SCq; }
          int c0 = s + u * 16 + ck;
          orow[c0]      = f2bf(o0);
          orow[c0 + 16] = f2bf(o1);
        }
      }
    }
  } else {
#pragma unroll
    for (int t = 0; t < 4; t++) {
      int rowb = bm + wr + t * 16 + quad * 4;
      if (rowb >= M) continue;
      int bb = (rowb >= nseq) ? 1 : 0;
      int posb = rowb - bb * nseq;
#pragma unroll
      for (int u = 0; u < 4; u++) {
        int cv = s - 384 + u * 16 + ck;
        int hh = cv >> 5, d = cv & 31;
        ushort4 o;
        o.x = f2bf(acc[t][u][0]);
        o.y = f2bf(acc[t][u][1]);
        o.z = f2bf(acc[t][u][2]);
        o.w = f2bf(acc[t][u][3]);
        *(ushort4*)(vt + ((size_t)((bb * 6 + hh) * 32 + d)) * nseqP + posb) = o;
      }
    }
  }
}

// ---------------- fused w1 GEMM (dbuf K-steps) + exact-GEGLU epilogue ----------------
__global__ __launch_bounds__(256) void gemm_w1g(
    const ushortT* __restrict__ A,
    const ushortT* __restrict__ Wt,       // [768][128] interleaved a/gate
    ushortT* __restrict__ gg,             // [M][GGP]
    int M) {
  __shared__ ushortT As[2][128 * 32];
  __shared__ ushortT Bs[2][128 * 32];
  const int tid = threadIdx.x;
  const int wid = tid >> 6, lane = tid & 63;
  const int ck = lane & 15, quad = lane >> 4;
  const int bm = blockIdx.y * 128, bn = blockIdx.x * 128;
  const int wr = (wid >> 1) * 64, wc = (wid & 1) * 64;
  f32x4 acc[4][4];
#pragma unroll
  for (int t = 0; t < 4; t++)
#pragma unroll
    for (int u = 0; u < 4; u++) acc[t][u] = (f32x4){0.f, 0.f, 0.f, 0.f};

  auto stage = [&](int bsel, int k0) {
#pragma unroll
    for (int c2 = 0; c2 < 2; c2++) {
      int idx = c2 * 256 + wid * 64 + lane;
      int row = idx >> 2, seg = (idx & 3) << 3;
      int ar = bm + row; if (ar > M - 1) ar = M - 1;
      async_copy16(A + (size_t)ar * 128 + k0 + seg,
                   As[bsel] + (size_t)(c2 * 256 + wid * 64) * 8);
      async_copy16(Wt + (size_t)(bn + row) * 128 + k0 + seg,
                   Bs[bsel] + (size_t)(c2 * 256 + wid * 64) * 8);
    }
  };

  stage(0, 0);
  __syncthreads();
  for (int t = 0; t < 4; t++) {
    const int cur = t & 1;
    if (t < 3) stage(cur ^ 1, (t + 1) * 32);
    bf16x8 af[4], bfr[4];
#pragma unroll
    for (int tt = 0; tt < 4; tt++)
      af[tt] = *(const bf16x8*)&As[cur][(wr + tt * 16 + ck) * 32 + quad * 8];
#pragma unroll
    for (int u = 0; u < 4; u++)
      bfr[u] = *(const bf16x8*)&Bs[cur][(wc + u * 16 + ck) * 32 + quad * 8];
#pragma unroll
    for (int tt = 0; tt < 4; tt++)
#pragma unroll
      for (int u = 0; u < 4; u++)
        acc[tt][u] = mfma16(af[tt], bfr[u], acc[tt][u]);
    __syncthreads();
  }

  const int s = bn + wc;
  if (s >= 704) return;
#pragma unroll
  for (int t = 0; t < 4; t++) {
#pragma unroll
    for (int r = 0; r < 4; r++) {
      int row = bm + wr + t * 16 + quad * 4 + r;
      if (row >= M) continue;
      ushortT* orow = gg + (size_t)row * GGP;
#pragma unroll
      for (int u = 0; u < 4; u += 2) {
        float a  = acc[t][u][r];
        float gt = acc[t][u + 1][r];
        float ge = 0.5f * gt * (1.0f + erff(gt * 0.70710678118654752f));
        int p = ((s + u * 16) >> 5) * 16 + ck;
        orow[p] = f2bf(a * ge);
      }
    }
  }
}

// ---------------- MFMA flash attention (R14-exact: 3-deep reg prefetch,
//                  swapped QK^T + permuted-K LDS in-register softmax,
//                  l-sum via ones-MFMA -> shuffle-free epilogue) ----------------
__global__ __launch_bounds__(256) void attn_kernel(
    const ushortT* __restrict__ qkh, const ushortT* __restrict__ vt,
    ushortT* __restrict__ out, int nseq, int nseqP, int w, int nw, int qgroups) {
  __shared__ __align__(16) ushortT Ks[2][64 * 32]; // [buf][perm key rows][32 d], swizzled
  __shared__ __align__(16) ushortT Vs[2][32 * 64]; // [buf][32 d][64 keys],       swizzled

  const int bx = blockIdx.x;
  const int c = bx % nw;                    // chunk -> XCD affinity
  const int g = (qgroups - 1) - bx / nw;    // heaviest q-groups launch first
  const int h = blockIdx.y;
  const int b = blockIdx.z;
  const int tid = threadIdx.x;
  const int wv = tid >> 6;
  const int lane = tid & 63;
  const int ck = lane & 15;
  const int quad = lane >> 4;

  const ushortT* gq = qkh + (size_t)b * nseq * 384;
  const ushortT* gv = vt + ((size_t)(b * 6 + h) * 32) * nseqP;
  const int cw = c * w;
  const int q0 = g * 64;
  const int qt = q0 + wv * 16;
  const bool wave_on = qt < w;

  const int j0 = (c > 0) ? (c - 1) * w : 0;
  const int jend_block = cw + min(q0 + 63, w - 1) + 1;
  const int jend_wave = wave_on ? (cw + min(qt + 15, w - 1) + 1) : 0;
  const int ntiles = (jend_block - j0 + 63) >> 6;

  bf16x8 qf;   // Q[qt+ck][d = quad*8..+7], serves as MFMA B operand (col = q)
  {
    int qrow = cw + min(qt + ck, w - 1);
    qf = *(const bf16x8*)(gq + (size_t)qrow * 384 + h * 32 + quad * 8);
  }

  // ---- staging addresses (setup-only) ----
  // K: thread stages logical key krow, d-chunk kch into permuted LDS row rho:
  // rho = 32*k5 + 16*k2 + 4*(k4k3) + (k1k0)  (bijective bit shuffle)
  const int krow = tid >> 2, kch = tid & 3;
  const int krho = ((krow >> 5) << 5) | (((krow >> 2) & 1) << 4) |
                   (((krow >> 3) & 3) << 2) | (krow & 3);
  const int kslot = krho * 4 + kch;
  const int kphys = kslot ^ ((kslot >> 3) & 7);
  const ushortT* ksrc = gq + (size_t)krow * 384 + 192 + h * 32 + kch * 8;
  // V: natural key order
  const int vphys = tid ^ ((tid >> 3) & 7);
  const ushortT* vsrc = gv + (size_t)(tid >> 3) * nseqP + (tid & 7) * 8;

  // ---- read addressing (halfword offsets into a 4KB buffer) ----
  // K A-fragment t: perm row 16t+ck, chunk quad -> slot 64t + ((4ck+quad)^(ck>>1))
  const int kbase = ((4 * ck + quad) ^ (ck >> 1)) * 8;
  // V B-fragment: row d=ck(+16), key-chunk quad (+4 for second 32 keys)
  const int p0 = ((8 * ck + quad) ^ (ck & 7)) * 8;
  const int p1 = p0 ^ 32;   // (8ck+quad+4): +4 == ^bit2 of slot == ^32 halfwords

  f32x4 olo = {0.f, 0.f, 0.f, 0.f};
  f32x4 ohi = {0.f, 0.f, 0.f, 0.f};
  f32x4 accl = {0.f, 0.f, 0.f, 0.f};
  bf16x8 onesf;
  {
    union { u32 u[4]; bf16x8 v; } o_;
    o_.u[0] = o_.u[1] = o_.u[2] = o_.u[3] = 0x3F803F80u;  // bf16(1.0) x2
    onesf = o_.v;
  }

  auto tileoff = [&](int t) -> int { return j0 + 64 * min(t, ntiles - 1); };

  // prologue: tile0 -> buf0 directly; X <- tile1, Y <- tile2 (clamped)
  float4 kX, vX, kY, vY;
  {
    float4 k0 = *(const float4*)(ksrc + (size_t)j0 * 384);
    float4 v0 = *(const float4*)(vsrc + j0);
    *(float4*)&Ks[0][(size_t)kphys * 8] = k0;
    *(float4*)&Vs[0][(size_t)vphys * 8] = v0;
    kX = *(const float4*)(ksrc + (size_t)tileoff(1) * 384);
    vX = *(const float4*)(vsrc + tileoff(1));
    kY = *(const float4*)(ksrc + (size_t)tileoff(2) * 384);
    vY = *(const float4*)(vsrc + tileoff(2));
  }

  auto compute = [&](const ushortT* KsB, const ushortT* VsB, int tb) {
    if (tb >= jend_wave) return;
    bf16x8 kf0 = *(const bf16x8*)&KsB[kbase];
    bf16x8 kf1 = *(const bf16x8*)&KsB[kbase + 512];
    bf16x8 kf2 = *(const bf16x8*)&KsB[kbase + 1024];
    bf16x8 kf3 = *(const bf16x8*)&KsB[kbase + 1536];
    bf16x8 vlo0 = *(const bf16x8*)&VsB[p0];
    bf16x8 vlo1 = *(const bf16x8*)&VsB[p1];
    bf16x8 vhi0 = *(const bf16x8*)&VsB[p0 + 1024];
    bf16x8 vhi1 = *(const bf16x8*)&VsB[p1 + 1024];
    f32x4 z = {0.f, 0.f, 0.f, 0.f};
    f32x4 s0 = mfma16(kf0, qf, z);   // D[perm-key][q]: lane holds q=qt+ck
    f32x4 s1 = mfma16(kf1, qf, z);
    f32x4 s2 = mfma16(kf2, qf, z);
    f32x4 s3 = mfma16(kf3, qf, z);
    // score (t,r): logical key = tb + 32*(t>>1) + 4*(t&1) + 8*quad + r
    if (tb + 63 > cw + qt) {
      int q = cw + qt + ck;
      int kb = tb + 8 * quad;
#pragma unroll
      for (int r = 0; r < 4; r++) {
        if (kb + r > q)      s0[r] = -__builtin_inff();
        if (kb + 4 + r > q)  s1[r] = -__builtin_inff();
        if (kb + 32 + r > q) s2[r] = -__builtin_inff();
        if (kb + 36 + r > q) s3[r] = -__builtin_inff();
      }
    }
    float e00 = exp2f(s0[0]), e01 = exp2f(s0[1]), e02 = exp2f(s0[2]), e03 = exp2f(s0[3]);
    float e10 = exp2f(s1[0]), e11 = exp2f(s1[1]), e12 = exp2f(s1[2]), e13 = exp2f(s1[3]);
    float e20 = exp2f(s2[0]), e21 = exp2f(s2[1]), e22 = exp2f(s2[2]), e23 = exp2f(s2[3]);
    float e30 = exp2f(s3[0]), e31 = exp2f(s3[1]), e32 = exp2f(s3[2]), e33 = exp2f(s3[3]);
    union { bf16x8 v; u32 u[4]; } pa0, pa1;
    pa0.u[0] = (u32)f2bf(e00) | ((u32)f2bf(e01) << 16);
    pa0.u[1] = (u32)f2bf(e02) | ((u32)f2bf(e03) << 16);
    pa0.u[2] = (u32)f2bf(e10) | ((u32)f2bf(e11) << 16);
    pa0.u[3] = (u32)f2bf(e12) | ((u32)f2bf(e13) << 16);
    pa1.u[0] = (u32)f2bf(e20) | ((u32)f2bf(e21) << 16);
    pa1.u[1] = (u32)f2bf(e22) | ((u32)f2bf(e23) << 16);
    pa1.u[2] = (u32)f2bf(e30) | ((u32)f2bf(e31) << 16);
    pa1.u[3] = (u32)f2bf(e32) | ((u32)f2bf(e33) << 16);
    olo  = mfma16(pa0.v, vlo0, olo);
    olo  = mfma16(pa1.v, vlo1, olo);
    ohi  = mfma16(pa0.v, vhi0, ohi);
    ohi  = mfma16(pa1.v, vhi1, ohi);
    accl = mfma16(pa0.v, onesf, accl);   // row-sum on the MFMA pipe
    accl = mfma16(pa1.v, onesf, accl);
  };

  // main loop, unrolled x2: reg set X serves odd-buf writes, Y even-buf writes.
  // A load issued at tile i is consumed (ds_write) at tile i+2 -> ~2-tile vmcnt slack.
  for (int i = 0; i < ntiles; i += 2) {
    __syncthreads();                       // even tile i: buf0 ready for reads
    *(float4*)&Ks[1][(size_t)kphys * 8] = kX;      // tile i+1 -> buf1
    *(float4*)&Vs[1][(size_t)vphys * 8] = vX;
    kX = *(const float4*)(ksrc + (size_t)tileoff(i + 3) * 384);
    vX = *(const float4*)(vsrc + tileoff(i + 3));
    compute(Ks[0], Vs[0], j0 + i * 64);

    __syncthreads();                       // odd tile i+1: buf1 ready for reads
    *(float4*)&Ks[0][(size_t)kphys * 8] = kY;      // tile i+2 -> buf0
    *(float4*)&Vs[0][(size_t)vphys * 8] = vY;
    kY = *(const float4*)(ksrc + (size_t)tileoff(i + 4) * 384);
    vY = *(const float4*)(vsrc + tileoff(i + 4));
    compute(Ks[1], Vs[1], j0 + (i + 1) * 64);
  }

  // epilogue: accl[r] is l for q = qt+quad*4+r (same layout as olo/ohi) -> no shuffles
  if (wave_on) {
#pragma unroll
    for (int r = 0; r < 4; r++) {
      int qi = qt + quad * 4 + r;
      if (qi < w) {
        float invr = 1.0f / accl[r];
        ushortT* orow = out + ((size_t)b * nseq + cw + qi) * INNER + h * 32;
        orow[ck]      = f2bf(olo[r] * invr);
        orow[ck + 16] = f2bf(ohi[r] * invr);
      }
    }
  }
}

// ---------------- merged setup: weights + conv bf16 + rope table ----------------
__global__ void wconvert_all_kernel(
    const float* __restrict__ dq, const float* __restrict__ dwo,
    const float* __restrict__ dw1, const float* __restrict__ dw2,
    const float* __restrict__ lq, const float* __restrict__ lwo,
    const float* __restrict__ lw1, const float* __restrict__ lw2,
    const float* __restrict__ convw,
    ushortT* __restrict__ wt, ushortT* __restrict__ cwt,
    float2* __restrict__ rope) {
  int idx = blockIdx.x * 256 + threadIdx.x;
  const int TOTW = 4 * (int)WT_SET;
  const int CWN = 128 * 256;
  if (idx < TOTW) {
    int s = idx / (int)WT_SET;
    int rem = idx - s * (int)WT_SET;
    int lyr = s & 1;
    const float* Wq = ((s < 2) ? dq : lq) + (size_t)lyr * DIM * QKV3;
    const float* Wo = ((s < 2) ? dwo : lwo) + (size_t)lyr * INNER * DIM;
    const float* W1 = ((s < 2) ? dw1 : lw1) + (size_t)lyr * DIM * FF2;
    const float* W2 = ((s < 2) ? dw2 : lw2) + (size_t)lyr * FFI * DIM;
    float v = 0.f;
    if (rem < (int)WT_WO) {                 // qkv: [640][128]
      int n = rem >> 7, k = rem & 127;
      if (n < QKV3) v = Wq[(size_t)k * QKV3 + n];
    } else if (rem < (int)WT_W1) {          // wo: [128][192]
      int r = rem - (int)WT_WO;
      int n = r / INNER, k = r - n * INNER;
      v = Wo[(size_t)k * DIM + n];
    } else if (rem < (int)WT_W2) {          // w1 interleaved: [768][128]
      int r = rem - (int)WT_W1;
      int n = r >> 7, k = r & 127;
      if (n < 704) {
        int blk = n >> 5, wi = n & 31;
        int p = blk * 16 + (wi & 15);
        if (p < FFI) {
          int src = (wi < 16) ? p : FFI + p;
          v = W1[(size_t)k * FF2 + src];
        }
      }
    } else {                                // w2: [128][352]
      int r = rem - (int)WT_W2;
      int n = r / GGP, k = r - n * GGP;
      if (k < FFI) v = W2[(size_t)k * DIM + n];
    }
    wt[idx] = f2bf(v);
  } else if (idx < TOTW + CWN) {
    // conv weights -> bf16 transposed: cwt[o][kk*128+i] = convw[(o*128+i)*2+kk]
    int r = idx - TOTW;
    int o = r >> 8, k = r & 255;
    int kk = k >> 7, i = k & 127;
    cwt[r] = f2bf(convw[((size_t)o * DIM + i) * 2 + kk]);
  } else {
    int r = idx - TOTW - CWN;
    if (r < N1 * 16) {
      int pos = r >> 4, k = r & 15;
      float invf = 1.0f / powf(10000.0f, (float)k * (1.0f / 16.0f));
      float sn, cs;
      sincosf((float)pos * invf, &sn, &cs);
      rope[r] = make_float2(cs, sn);
    }
  }
}

// ---------------- host-side layer driver ----------------
// hbuf = this layer's LN1 input activations (bf16). wo fuses ln2 -> hbuf;
// w2 fuses next-layer ln1 -> hbuf (if nlnw) and/or writes bf16 mirror (w2bf).
static void run_layer(float* F, float* Fout, ushortT* hbuf, ushortT* qkh, ushortT* vtb,
                      ushortT* attnb, ushortT* ggb, const ushortT* wt,
                      const float2* rope,
                      int M, int nseq, int w,
                      const float* ln2w, const float* ln2b,
                      const float* nlnw, const float* nlnb,
                      ushortT* w2bf, hipStream_t stream) {
  int nseqP = nseq + 128;
  int gy = (M + 127) / 128;
  int gy64 = M / 64;
  gemm_qkv<<<dim3(5, gy), 256, 0, stream>>>(hbuf, wt + WT_QKV, rope, qkh, vtb, M, nseq, nseqP);
  int nw = nseq / w;
  int qgroups = (w + 63) / 64;
  attn_kernel<<<dim3(nw * qgroups, HEADS, BATCH), 256, 0, stream>>>(qkh, vtb, attnb,
                                                                    nseq, nseqP, w, nw, qgroups);
  gemm_nln<<<dim3(1, gy64), 256, 0, stream>>>(attnb, INNER, wt + WT_WO, INNER, F, F,
                                              nullptr, M, INNER, 1, ln2w, ln2b,
                                              hbuf, nullptr);
  gemm_w1g<<<dim3(6, gy), 256, 0, stream>>>(hbuf, wt + WT_W1, ggb, M);
  gemm_nln<<<dim3(1, gy64), 256, 0, stream>>>(ggb, GGP, wt + WT_W2, GGP, F, Fout,
                                              nullptr, M, GGP, 1, nlnw, nlnb,
                                              nlnw ? hbuf : (ushortT*)nullptr, w2bf);
}

extern "C" void kernel_launch(void* const* d_in, const int* in_sizes, int n_in,
                              void* d_out, int out_size, void* d_ws, size_t ws_size,
                              hipStream_t stream) {
  const float* x        = (const float*)d_in[0];
  const float* cache    = (const float*)d_in[1];
  const float* dt_ln1_w = (const float*)d_in[2];
  const float* dt_ln1_b = (const float*)d_in[3];
  const float* dt_wqkv  = (const float*)d_in[4];
  const float* dt_wo    = (const float*)d_in[5];
  const float* dt_ln2_w = (const float*)d_in[6];
  const float* dt_ln2_b = (const float*)d_in[7];
  const float* dt_w1    = (const float*)d_in[8];
  const float* dt_w2    = (const float*)d_in[9];
  const float* lt_ln1_w = (const float*)d_in[10];
  const float* lt_ln1_b = (const float*)d_in[11];
  const float* lt_wqkv  = (const float*)d_in[12];
  const float* lt_wo    = (const float*)d_in[13];
  const float* lt_ln2_w = (const float*)d_in[14];
  const float* lt_ln2_b = (const float*)d_in[15];
  const float* lt_w1    = (const float*)d_in[16];
  const float* lt_w2    = (const float*)d_in[17];
  const float* conv_w   = (const float*)d_in[18];
  const float* conv_b   = (const float*)d_in[19];

  float* ws     = (float*)d_ws;
  float* feat   = ws + OF_FEAT;
  ushortT* h    = (ushortT*)(ws + OF_H);
  ushortT* qkh  = (ushortT*)(ws + OF_QKH);
  ushortT* attnb= (ushortT*)(ws + OF_AO);
  ushortT* vtb  = (ushortT*)(ws + OF_VT);
  ushortT* ggb  = (ushortT*)(ws + OF_GG);
  float* feat2  = ws + OF_F2;
  ushortT* wt   = (ushortT*)(ws + OF_WT);
  ushortT* cwt  = (ushortT*)(ws + OF_CW);
  float2* rope  = (float2*)(ws + OF_ROPE);
  ushortT* h2   = (ushortT*)(ws + OF_H2);
  float* outf   = (float*)d_out;

  {
    int total = 4 * (int)WT_SET + 128 * 256 + N1 * 16;
    wconvert_all_kernel<<<(total + 255) / 256, 256, 0, stream>>>(
        dt_wqkv, dt_wo, dt_w1, dt_w2, lt_wqkv, lt_wo, lt_w1, lt_w2,
        conv_w, wt, cwt, rope);
  }

  build_feat_kernel<<<(ROWS1 * DIM + 255) / 256, 256, 0, stream>>>(x, cache, feat);
  ln_kernel<<<ROWS1 / 4, 256, 0, stream>>>(feat, h, dt_ln1_w, dt_ln1_b, ROWS1);

  // DT layer 0: w2 fuses DT layer-1 ln1 into h
  run_layer(feat, feat, h, qkh, vtb, attnb, ggb, wt + 0 * WT_SET, rope,
            ROWS1, N1, W_DT,
            dt_ln2_w, dt_ln2_b, dt_ln1_w + DIM, dt_ln1_b + DIM, nullptr, stream);
  // DT layer 1: w2 skips the fp32 store; writes bf16 result into h for the conv
  run_layer(feat, nullptr, h, qkh, vtb, attnb, ggb, wt + 1 * WT_SET, rope,
            ROWS1, N1, W_DT,
            dt_ln2_w + DIM, dt_ln2_b + DIM, nullptr, nullptr, h, stream);

  // conv as bf16 MFMA GEMM (K=256 over adjacent row pairs) + fused lt ln1 -> h2
  gemm_nln<<<dim3(1, ROWS2 / 64), 256, 0, stream>>>(h, 256, cwt, 256,
                                                    feat2, feat2, conv_b,
                                                    ROWS2, 256, 0,
                                                    lt_ln1_w, lt_ln1_b, h2, nullptr);

  // LT layer 0: w2 fuses LT layer-1 ln1 into h2
  run_layer(feat2, feat2, h2, qkh, vtb, attnb, ggb, wt + 2 * WT_SET, rope,
            ROWS2, N2, W_LT,
            lt_ln2_w, lt_ln2_b, lt_ln1_w + DIM, lt_ln1_b + DIM, nullptr, stream);
  // LT layer 1: final w2 writes d_out directly
  run_layer(feat2, outf, h2, qkh, vtb, attnb, ggb, wt + 3 * WT_SET, rope,
            ROWS2, N2, W_LT,
            lt_ln2_w + DIM, lt_ln2_b + DIM, nullptr, nullptr, nullptr, stream);
}